// Round 21
// baseline (341.505 us; speedup 1.0000x reference)
//
#include <hip/hip_runtime.h>

// ES gradient for 2-layer MLP (D_IN=1024, HID=2048, D_OUT=10, POP=40, STD=0.1).
// Pipeline: k_xsplit -> k_base -> k_big32 (or k_big64 fallback) -> k_loss ->
// k_rank -> k_grad.
// k_big32 v4 = R20's spill-free 128-VGPR kernel + s_setprio(1) around the
// MFMA cluster (T5: pays in role-split schedules; waves 0-1 stage, 2-3 don't).
// Laws measured this session:
//  - E-stream BW tracks waves/CU (VGPR 256 -> ~1.0-1.2 TB/s; 128 -> ~1.7-2.05).
//  - VGPR cap = 256/launch_bounds_arg2; demand>cap -> deterministic spill
//    (WRITE_SIZE tripwire). Loop fits 128; R20's nf-outer epilogue fits 128.
//  - Raw s_barrier + lgkmcnt(0) keeps global loads in flight across barriers.
//  - Rank-exactness: 2-product split (E hi/lo f16 x x f16): absmax 2.441e-4.

#define NPLL 2119690LL          // N_PARAMS
#define S1_  2097152            // W1 end
#define S2_  2099200            // b1 end
#define S3_  2119680            // W2 end

// narrow ws layout (f32 units), jt32 fallback:
#define WS_PP   524288
#define WS_LOSS 3801088
#define WS_G    3801168
#define WS_XF   3801216
// wide ws layout (f32 units), jt64: base | ppu 6553600 dw | loss | g | xf
#define WW_PP   524288
#define WW_LOSS 7077888
#define WW_G    7077968
#define WW_XF   7078016
#define WW_NEED_BYTES 28836352ull   // (WW_XF + 131072) * 4

typedef _Float16 f16;
typedef __fp16   fp16x2 __attribute__((ext_vector_type(2)));
typedef _Float16 f16x2t __attribute__((ext_vector_type(2)));
typedef _Float16 f16x8 __attribute__((ext_vector_type(8)));
typedef float    f32x4 __attribute__((ext_vector_type(4)));

__device__ __forceinline__ unsigned pk2r(float a, float b, float& ra, float& rb) {
  fp16x2 h = __builtin_amdgcn_cvt_pkrtz(a, b);   // RTZ pack
  ra = a - (float)h[0];
  rb = b - (float)h[1];
  return __builtin_bit_cast(unsigned, h);
}
__device__ __forceinline__ unsigned pk2(float a, float b) {
  fp16x2 h = __builtin_amdgcn_cvt_pkrtz(a, b);
  return __builtin_bit_cast(unsigned, h);
}
__device__ __forceinline__ unsigned packh(float a, float b) {  // RTN pack
  f16x2t v = {(f16)a, (f16)b};
  return __builtin_bit_cast(unsigned, v);
}
__device__ __forceinline__ float unpk_lo(unsigned u) {
  return (float)__builtin_bit_cast(f16, (unsigned short)(u & 0xffffu));
}
__device__ __forceinline__ float unpk_hi(unsigned u) {
  return (float)__builtin_bit_cast(f16, (unsigned short)(u >> 16));
}

// ---------------- k_xsplit: x -> fragment-order f16 (RTN) -------------------
__global__ __launch_bounds__(256) void k_xsplit(const float* __restrict__ x,
                                                f16* __restrict__ xf) {
  const int idx = blockIdx.x * 256 + threadIdx.x;  // 32768
  const int b  = idx >> 7;
  const int k8 = idx & 127;
  const int kt = k8 >> 2, qh = k8 & 3;
  const int bblk = b >> 4, lm = b & 15;
  float4 a0 = *(const float4*)&x[(size_t)b * 1024 + k8 * 8];
  float4 a1 = *(const float4*)&x[(size_t)b * 1024 + k8 * 8 + 4];
  uint4 H;
  H.x = packh(a0.x, a0.y);
  H.y = packh(a0.z, a0.w);
  H.z = packh(a1.x, a1.y);
  H.w = packh(a1.z, a1.w);
  f16* dst = &xf[(((size_t)(kt * 16 + bblk) * 4 + qh) * 16 + lm) * 8];
  *(uint4*)dst = H;
}

// ---------------- k_base: base[j][b] = (x @ W1)[b][j] + b1[j] (fp32) --------
__global__ __launch_bounds__(256) void k_base(const float* __restrict__ x,
                                              const float* __restrict__ W1,
                                              const float* __restrict__ b1,
                                              float* __restrict__ base) {
  constexpr int STR = 72;
  __shared__ float xsm[32 * STR];
  __shared__ float es[32 * STR];
  const int t  = threadIdx.x;
  const int j0 = blockIdx.x * 64;
  const int b0 = blockIdx.y * 32;
  const int tj = t & 15;
  const int tb = t >> 4;
  float acc[4][2] = {};
  for (int k0 = 0; k0 < 1024; k0 += 32) {
    __syncthreads();
    {
      int bb = t >> 3, kq = t & 7;
      float4 v = *(const float4*)&x[(size_t)(b0 + bb) * 1024 + k0 + kq * 4];
      int kb = kq * 4;
      xsm[(kb + 0) * STR + bb] = v.x;
      xsm[(kb + 1) * STR + bb] = v.y;
      xsm[(kb + 2) * STR + bb] = v.z;
      xsm[(kb + 3) * STR + bb] = v.w;
    }
#pragma unroll
    for (int r = 0; r < 2; ++r) {
      int idx = t + r * 256;
      int k = idx >> 4, jq = idx & 15, col = jq * 4;
      float4 v = *(const float4*)&W1[(size_t)(k0 + k) * 2048 + j0 + col];
      *(float4*)&es[k * STR + col + 4 * (col >> 5)] = v;
    }
    __syncthreads();
#pragma unroll 8
    for (int k = 0; k < 32; ++k) {
      const int ce = tj * 4;
      float4 e = *(const float4*)&es[k * STR + ce + 4 * (ce >> 5)];
      float2 a = *(const float2*)&xsm[k * STR + tb * 2];
      acc[0][0] += e.x * a.x; acc[0][1] += e.x * a.y;
      acc[1][0] += e.y * a.x; acc[1][1] += e.y * a.y;
      acc[2][0] += e.z * a.x; acc[2][1] += e.z * a.y;
      acc[3][0] += e.w * a.x; acc[3][1] += e.w * a.y;
    }
  }
#pragma unroll
  for (int jj = 0; jj < 4; ++jj) {
    int j = j0 + tj * 4 + jj;
    float bv = b1[j];
    float2 o = make_float2(acc[jj][0] + bv, acc[jj][1] + bv);
    *(float2*)&base[(size_t)j * 256 + b0 + tb * 2] = o;
  }
}

// ======= k_big32 v4: j32 x b256 tiles, wave 32j x 64b, VGPR cap 128 =========
// grid (64 jt, 40 p), 256 threads = 4 waves. eA [32 j][64 f16] x 2 (4 KB ea).
// Waves 0-1 stage E (uint4 XOR conflict-free, 2-deep prefetch). RAW barrier/
// step, vmcnt never drained in-loop. s_setprio(1) around MFMA cluster (T5).
// NF-OUTER streaming epilogue (fits the 128 cap; R20 verified spill-free).
__global__ __launch_bounds__(256, 2) void k_big32(const f16* __restrict__ xf,
                                                  const float* __restrict__ noise,
                                                  const float* __restrict__ W2,
                                                  const float* __restrict__ base,
                                                  unsigned* __restrict__ ppu) {
  __shared__ __align__(16) char smem[8192];   // eA[0] | eA[1] (4 KB each)
  float* w2l = (float*)smem;       // epilogue overlay (2.7 KB)
  float* e2l = w2l + 320;
  float* e1l = e2l + 320;

  const int t    = threadIdx.x;
  const int jt   = blockIdx.x, p = blockIdx.y;
  const int j0   = jt * 32;
  const int wave = t >> 6, lane = t & 63;
  const int lm   = lane & 15, qh = lane >> 4;
  const int g4   = qh * 4;
  const int bw   = wave * 64;
  const size_t pN = (size_t)p * NPLL;
  const bool stager = (t < 128);               // waves 0-1
  const int srow = t & 31, sq = (t >> 5) & 3;  // staging j-row / k-octet
  const int sswz = (srow & 7) << 3;
  const int aswz = (lm & 7) << 3;

  f16* eA0 = (f16*)smem;
  f16* eA1 = (f16*)(smem + 4096);

  float veA[8], veB[8];
  f16x8 Ba[4], Bb[4];
  f32x4 acc[2][4];
#pragma unroll
  for (int a = 0; a < 2; ++a)
#pragma unroll
    for (int b = 0; b < 4; ++b) acc[a][b] = (f32x4){0.f, 0.f, 0.f, 0.f};

  const float* Ebase = noise + pN + (size_t)(sq * 8) * 2048 + j0 + srow;
  const int boff = (wave * 4) * 512 + qh * 128 + lm * 8;

  // prologue: loads for ks = 0 (veA/Ba) and ks = 1 (veB/Bb)
  if (stager) {
#pragma unroll
    for (int d = 0; d < 8; ++d) veA[d] = Ebase[(size_t)d * 2048];
#pragma unroll
    for (int d = 0; d < 8; ++d) veB[d] = Ebase[65536 + (size_t)d * 2048];
  }
#pragma unroll
  for (int nf = 0; nf < 4; ++nf)
    Ba[nf] = *(const f16x8*)&xf[boff + nf * 512];
#pragma unroll
  for (int nf = 0; nf < 4; ++nf)
    Bb[nf] = *(const f16x8*)&xf[8192 + boff + nf * 512];

#define KSTEP32(EAC, VE, BF, KS)                                               \
  do {                                                                         \
    if (stager) {                                                              \
      float r0, r1, r2, r3, r4, r5, r6, r7;                                    \
      uint4 H, L;                                                              \
      H.x = pk2r(VE[0], VE[1], r0, r1);                                        \
      H.y = pk2r(VE[2], VE[3], r2, r3);                                        \
      H.z = pk2r(VE[4], VE[5], r4, r5);                                        \
      H.w = pk2r(VE[6], VE[7], r6, r7);                                        \
      *(uint4*)&EAC[srow * 64 + ((sq * 8) ^ sswz)] = H;                        \
      L.x = pk2(r0, r1); L.y = pk2(r2, r3);                                    \
      L.z = pk2(r4, r5); L.w = pk2(r6, r7);                                    \
      *(uint4*)&EAC[srow * 64 + (((sq + 4) * 8) ^ sswz)] = L;                  \
      if ((KS) + 2 < 32) {                                                     \
        const float* En = Ebase + (size_t)((KS) + 2) * 65536;                  \
        _Pragma("unroll") for (int d = 0; d < 8; ++d)                          \
          VE[d] = En[(size_t)d * 2048];                                        \
      }                                                                        \
    }                                                                          \
    asm volatile("s_waitcnt lgkmcnt(0)" ::: "memory");  /* ds_writes done */   \
    __builtin_amdgcn_s_barrier();                       /* raw: no vm drain */ \
    asm volatile("" ::: "memory");                                             \
    __builtin_amdgcn_s_setprio(1);                      /* favor MFMA wave */  \
    _Pragma("unroll") for (int mf = 0; mf < 2; ++mf) {                         \
      const int ra = mf * 16 + lm;                                             \
      f16x8 Ah = *(const f16x8*)&EAC[ra * 64 + ((qh * 8) ^ aswz)];             \
      f16x8 Al = *(const f16x8*)&EAC[ra * 64 + (((qh + 4) * 8) ^ aswz)];       \
      _Pragma("unroll") for (int nf = 0; nf < 4; ++nf) {                       \
        acc[mf][nf] = __builtin_amdgcn_mfma_f32_16x16x32_f16(Ah, BF[nf], acc[mf][nf], 0, 0, 0); \
        acc[mf][nf] = __builtin_amdgcn_mfma_f32_16x16x32_f16(Al, BF[nf], acc[mf][nf], 0, 0, 0); \
      }                                                                        \
    }                                                                          \
    __builtin_amdgcn_s_setprio(0);                                             \
    if ((KS) + 2 < 32) {                                                       \
      const f16* xn = xf + (size_t)((KS) + 2) * 8192;                          \
      _Pragma("unroll") for (int nf = 0; nf < 4; ++nf)                         \
        BF[nf] = *(const f16x8*)&xn[boff + nf * 512];                          \
    }                                                                          \
  } while (0)

  for (int ks = 0; ks < 32; ks += 2) {
    KSTEP32(eA0, veA, Ba, ks);
    KSTEP32(eA1, veB, Bb, ks + 1);
  }
#undef KSTEP32

  // ---- epilogue: tables overlay dead eA; NF-OUTER streaming (low live) ----
  __syncthreads();
  for (int i = t; i < 320; i += 256) {
    w2l[i] = W2[j0 * 10 + i];
    e2l[i] = noise[pN + S2_ + (size_t)j0 * 10 + i];
  }
  if (t < 32) e1l[t] = noise[pN + S1_ + j0 + t];
  __syncthreads();

#pragma unroll 1
  for (int s = 0; s < 2; ++s) {
    const float sf = s ? -0.1f : 0.1f;
#pragma unroll 1
    for (int nf = 0; nf < 4; ++nf) {
      const int bl = bw + nf * 16 + lm;
      float ppv[10];
#pragma unroll
      for (int o = 0; o < 10; ++o) ppv[o] = 0.f;
#pragma unroll
      for (int mf = 0; mf < 2; ++mf)
#pragma unroll
        for (int r = 0; r < 4; ++r) {
          const int jl = mf * 16 + g4 + r;     // D row = (lane>>4)*4 + reg
          const float bs = base[(size_t)(j0 + jl) * 256 + bl];
          const float h =
              fmaxf(fmaf(sf, acc[mf][nf][r] + e1l[jl], bs), 0.f);
#pragma unroll
          for (int o = 0; o < 10; ++o)
            ppv[o] = fmaf(h, fmaf(sf, e2l[jl * 10 + o], w2l[jl * 10 + o]),
                          ppv[o]);
        }
      // sum the 4 qh row-groups (lane bits 4,5); wave covers all 32 j
#pragma unroll
      for (int o = 0; o < 10; ++o) {
        float v = ppv[o];
        v += __shfl_xor(v, 16, 64);
        v += __shfl_xor(v, 32, 64);
        ppv[o] = v;
      }
      if (lane < 16) {
        const size_t u0 = ((((size_t)p * 2 + s) * 64 + jt) * 256 + bl) * 5;
        ppu[u0 + 0] = packh(ppv[0], ppv[1]);
        ppu[u0 + 1] = packh(ppv[2], ppv[3]);
        ppu[u0 + 2] = packh(ppv[4], ppv[5]);
        ppu[u0 + 3] = packh(ppv[6], ppv[7]);
        ppu[u0 + 4] = packh(ppv[8], ppv[9]);
      }
    }
  }
}

// ======= k_big64: R12's verified kernel (fallback when ws is small) =========
__global__ __launch_bounds__(256) void k_big64(const f16* __restrict__ xf,
                                               const float* __restrict__ noise,
                                               const float* __restrict__ W2,
                                               const float* __restrict__ base,
                                               unsigned* __restrict__ ppu) {
  __shared__ __align__(16) char smem[16384];
  float* w2l = (float*)smem;
  float* e2l = w2l + 640;
  float* e1l = e2l + 640;

  const int t    = threadIdx.x;
  const int jt   = blockIdx.x, p = blockIdx.y;
  const int j0   = jt * 64;
  const int wave = t >> 6, lane = t & 63;
  const int lm   = lane & 15, qh = lane >> 4;
  const int g4   = qh * 4;
  const int bw   = wave * 64;
  const size_t pN = (size_t)p * NPLL;
  const int srow = t & 63, sq = t >> 6;
  const int sswz = (srow & 7) << 3;
  const int aswz = (lm & 7) << 3;

  f16* eA0 = (f16*)smem;
  f16* eA1 = (f16*)(smem + 8192);

  float veA[8], veB[8];
  f16x8 Ba[4], Bb[4];
  f32x4 acc[4][4];
#pragma unroll
  for (int a = 0; a < 4; ++a)
#pragma unroll
    for (int b = 0; b < 4; ++b) acc[a][b] = (f32x4){0.f, 0.f, 0.f, 0.f};

  const float* Ebase = noise + pN + (size_t)(sq * 8) * 2048 + j0 + srow;
  const int boff = (wave * 4) * 512 + qh * 128 + lm * 8;

#pragma unroll
  for (int d = 0; d < 8; ++d) veA[d] = Ebase[(size_t)d * 2048];
#pragma unroll
  for (int nf = 0; nf < 4; ++nf)
    Ba[nf] = *(const f16x8*)&xf[boff + nf * 512];
#pragma unroll
  for (int d = 0; d < 8; ++d) veB[d] = Ebase[65536 + (size_t)d * 2048];
#pragma unroll
  for (int nf = 0; nf < 4; ++nf)
    Bb[nf] = *(const f16x8*)&xf[8192 + boff + nf * 512];

#define KSTEP64(EAC, VE, BF, KS)                                               \
  do {                                                                         \
    {                                                                          \
      float r0, r1, r2, r3, r4, r5, r6, r7;                                    \
      uint4 H, L;                                                              \
      H.x = pk2r(VE[0], VE[1], r0, r1);                                        \
      H.y = pk2r(VE[2], VE[3], r2, r3);                                        \
      H.z = pk2r(VE[4], VE[5], r4, r5);                                        \
      H.w = pk2r(VE[6], VE[7], r6, r7);                                        \
      *(uint4*)&EAC[srow * 64 + ((sq * 8) ^ sswz)] = H;                        \
      L.x = pk2(r0, r1); L.y = pk2(r2, r3);                                    \
      L.z = pk2(r4, r5); L.w = pk2(r6, r7);                                    \
      *(uint4*)&EAC[srow * 64 + (((sq + 4) * 8) ^ sswz)] = L;                  \
    }                                                                          \
    if ((KS) + 2 < 32) {                                                       \
      const float* En = Ebase + (size_t)((KS) + 2) * 65536;                    \
      _Pragma("unroll") for (int d = 0; d < 8; ++d)                            \
        VE[d] = En[(size_t)d * 2048];                                          \
    }                                                                          \
    asm volatile("s_waitcnt lgkmcnt(0)" ::: "memory");                         \
    __builtin_amdgcn_s_barrier();                                              \
    asm volatile("" ::: "memory");                                             \
    _Pragma("unroll") for (int mf = 0; mf < 4; ++mf) {                         \
      const int ra = mf * 16 + lm;                                             \
      f16x8 Ah = *(const f16x8*)&EAC[ra * 64 + ((qh * 8) ^ aswz)];             \
      f16x8 Al = *(const f16x8*)&EAC[ra * 64 + (((qh + 4) * 8) ^ aswz)];       \
      _Pragma("unroll") for (int nf = 0; nf < 4; ++nf) {                       \
        acc[mf][nf] = __builtin_amdgcn_mfma_f32_16x16x32_f16(Ah, BF[nf], acc[mf][nf], 0, 0, 0); \
        acc[mf][nf] = __builtin_amdgcn_mfma_f32_16x16x32_f16(Al, BF[nf], acc[mf][nf], 0, 0, 0); \
      }                                                                        \
    }                                                                          \
    if ((KS) + 2 < 32) {                                                       \
      const f16* xn = xf + (size_t)((KS) + 2) * 8192;                          \
      _Pragma("unroll") for (int nf = 0; nf < 4; ++nf)                         \
        BF[nf] = *(const f16x8*)&xn[boff + nf * 512];                          \
    }                                                                          \
  } while (0)

  for (int ks = 0; ks < 32; ks += 2) {
    KSTEP64(eA0, veA, Ba, ks);
    KSTEP64(eA1, veB, Bb, ks + 1);
  }
#undef KSTEP64

  __syncthreads();
  for (int i = t; i < 640; i += 256) {
    w2l[i] = W2[j0 * 10 + i];
    e2l[i] = noise[pN + S2_ + (size_t)j0 * 10 + i];
  }
  if (t < 64) e1l[t] = noise[pN + S1_ + j0 + t];
  __syncthreads();

#pragma unroll 1
  for (int s = 0; s < 2; ++s) {
    const float sf = s ? -0.1f : 0.1f;
    float ppv[4][10];
#pragma unroll
    for (int nf = 0; nf < 4; ++nf)
#pragma unroll
      for (int o = 0; o < 10; ++o) ppv[nf][o] = 0.f;
#pragma unroll
    for (int mf = 0; mf < 4; ++mf)
#pragma unroll
      for (int r = 0; r < 4; ++r) {
        const int jl = mf * 16 + g4 + r;
        const float e1v = e1l[jl];
        float w2s[10];
#pragma unroll
        for (int o = 0; o < 10; ++o)
          w2s[o] = fmaf(sf, e2l[jl * 10 + o], w2l[jl * 10 + o]);
#pragma unroll
        for (int nf = 0; nf < 4; ++nf) {
          const float bs = base[(size_t)(j0 + jl) * 256 + bw + nf * 16 + lm];
          const float h = fmaxf(fmaf(sf, acc[mf][nf][r] + e1v, bs), 0.f);
#pragma unroll
          for (int o = 0; o < 10; ++o) ppv[nf][o] = fmaf(h, w2s[o], ppv[nf][o]);
        }
      }
#pragma unroll
    for (int nf = 0; nf < 4; ++nf)
#pragma unroll
      for (int o = 0; o < 10; ++o) {
        float v = ppv[nf][o];
        v += __shfl_xor(v, 16, 64);
        v += __shfl_xor(v, 32, 64);
        ppv[nf][o] = v;
      }
    if (lane < 16) {
#pragma unroll
      for (int nf = 0; nf < 4; ++nf) {
        const int bl = bw + nf * 16 + lm;
        const size_t u0 = ((((size_t)p * 2 + s) * 32 + jt) * 256 + bl) * 5;
        ppu[u0 + 0] = packh(ppv[nf][0], ppv[nf][1]);
        ppu[u0 + 1] = packh(ppv[nf][2], ppv[nf][3]);
        ppu[u0 + 2] = packh(ppv[nf][4], ppv[nf][5]);
        ppu[u0 + 3] = packh(ppv[nf][6], ppv[nf][7]);
        ppu[u0 + 4] = packh(ppv[nf][8], ppv[nf][9]);
      }
    }
  }
}

// ---------------- k_loss: 80 losses (JT-parameterized) ----------------------
__global__ __launch_bounds__(256) void k_loss(const unsigned* __restrict__ ppu,
                                              const float* __restrict__ y,
                                              const float* __restrict__ b2,
                                              const float* __restrict__ noise,
                                              float* __restrict__ loss,
                                              int JT) {
  const int b = threadIdx.x;
  const int p = blockIdx.x >> 1, s = blockIdx.x & 1;
  const float sf = s ? -0.1f : 0.1f;
  const size_t pN = (size_t)p * NPLL;
  float pred[10];
#pragma unroll
  for (int o = 0; o < 10; ++o) pred[o] = b2[o] + sf * noise[pN + S3_ + o];
  for (int jt = 0; jt < JT; ++jt) {
    const size_t u0 = ((((size_t)p * 2 + s) * JT + jt) * 256 + b) * 5;
#pragma unroll
    for (int q = 0; q < 5; ++q) {
      unsigned u = ppu[u0 + q];
      pred[2 * q]     += unpk_lo(u);
      pred[2 * q + 1] += unpk_hi(u);
    }
  }
  float e = 0.f;
#pragma unroll
  for (int o = 0; o < 10; ++o) {
    float d = pred[o] - y[b * 10 + o];
    e += d * d;
  }
  __shared__ float red[256];
  red[b] = e;
  __syncthreads();
  for (int st = 128; st > 0; st >>= 1) {
    if (b < st) red[b] += red[b + st];
    __syncthreads();
  }
  if (b == 0) loss[blockIdx.x] = red[0] * (1.0f / 2560.0f);
}

// ---------------- k_rank: stable centered ranks -> pair coefficients --------
__global__ void k_rank(const float* __restrict__ loss, float* __restrict__ g) {
  __shared__ float ls[80];
  __shared__ float rk[80];
  const int t = threadIdx.x;
  if (t < 80) ls[t] = loss[t];
  __syncthreads();
  if (t < 80) {
    float li = ls[t];
    int r = 0;
    for (int j = 0; j < 80; ++j) {
      float lj = ls[j];
      r += (lj < li) || (lj == li && j < t);
    }
    rk[t] = (float)r;
  }
  __syncthreads();
  if (t < 40) g[t] = (rk[2 * t] - rk[2 * t + 1]) * (1.0f / (79.0f * 40.0f));
}

// ---------------- k_grad: out[k] = sum_p noise[p][k] * g[p] -----------------
__global__ __launch_bounds__(256) void k_grad(const float* __restrict__ noise,
                                              const float* __restrict__ g,
                                              float* __restrict__ out) {
  __shared__ float gg[40];
  const int t = threadIdx.x;
  if (t < 40) gg[t] = g[t];
  __syncthreads();
  const long long NH = NPLL / 2;
  long long idx = (long long)blockIdx.x * 256 + t;
  if (idx >= NH) return;
  float2 a = make_float2(0.f, 0.f);
#pragma unroll 8
  for (int p = 0; p < 40; ++p) {
    float2 v = *(const float2*)&noise[(size_t)p * NPLL + idx * 2];
    a.x += v.x * gg[p];
    a.y += v.y * gg[p];
  }
  *(float2*)&out[idx * 2] = a;
}

extern "C" void kernel_launch(void* const* d_in, const int* in_sizes, int n_in,
                              void* d_out, int out_size, void* d_ws, size_t ws_size,
                              hipStream_t stream) {
  const float* x     = (const float*)d_in[0];
  const float* y     = (const float*)d_in[1];
  const float* W1    = (const float*)d_in[2];
  const float* b1    = (const float*)d_in[3];
  const float* W2    = (const float*)d_in[4];
  const float* b2    = (const float*)d_in[5];
  const float* noise = (const float*)d_in[6];
  float* out  = (float*)d_out;
  float* ws   = (float*)d_ws;
  float* base = ws;

  const bool wide = (ws_size >= WW_NEED_BYTES);
  unsigned* ppu = (unsigned*)(ws + (wide ? WW_PP : WS_PP));
  float* loss = ws + (wide ? WW_LOSS : WS_LOSS);
  float* g    = ws + (wide ? WW_G : WS_G);
  f16* xf     = (f16*)(ws + (wide ? WW_XF : WS_XF));

  k_xsplit<<<128, 256, 0, stream>>>(x, xf);
  k_base<<<dim3(32, 8), 256, 0, stream>>>(x, W1, b1, base);
  if (wide)
    k_big32<<<dim3(64, 40), 256, 0, stream>>>(xf, noise, W2, base, ppu);
  else
    k_big64<<<dim3(32, 40), 256, 0, stream>>>(xf, noise, W2, base, ppu);
  k_loss<<<80, 256, 0, stream>>>(ppu, y, b2, noise, loss, wide ? 64 : 32);
  k_rank<<<1, 128, 0, stream>>>(loss, g);
  k_grad<<<4141, 256, 0, stream>>>(noise, g, out);
}

// Round 22
// 336.092 us; speedup vs baseline: 1.0161x; 1.0161x over previous
//
#include <hip/hip_runtime.h>

// ES gradient for 2-layer MLP (D_IN=1024, HID=2048, D_OUT=10, POP=40, STD=0.1).
// Pipeline: k_xsplit -> k_base -> k_big32 (or k_big64 fallback) -> k_loss ->
// k_rank -> k_grad.
// k_big32 v5 = R20's spill-free 128-VGPR kernel with ALL-WAVE staging (each
// thread 4 E-dwords/step) + DEPTH-4 E prefetch: 2x issue waves x 2x depth =
// 4x E-requests in flight per CU. setprio removed (R21: null).
// Laws measured this session:
//  - E-stream BW tracks waves/CU AND issue parallelism (this tests the latter).
//  - VGPR cap = 256/launch_bounds_arg2; demand>cap -> deterministic spill
//    (WRITE_SIZE tripwire). R20's nf-outer epilogue + this loop fit 128.
//  - Raw s_barrier + lgkmcnt(0) keeps global loads in flight across barriers.
//  - Rank-exactness: 2-product split (E hi/lo f16 x x f16): absmax 2.441e-4.

#define NPLL 2119690LL          // N_PARAMS
#define S1_  2097152            // W1 end
#define S2_  2099200            // b1 end
#define S3_  2119680            // W2 end

// narrow ws layout (f32 units), jt32 fallback:
#define WS_PP   524288
#define WS_LOSS 3801088
#define WS_G    3801168
#define WS_XF   3801216
// wide ws layout (f32 units), jt64: base | ppu 6553600 dw | loss | g | xf
#define WW_PP   524288
#define WW_LOSS 7077888
#define WW_G    7077968
#define WW_XF   7078016
#define WW_NEED_BYTES 28836352ull   // (WW_XF + 131072) * 4

typedef _Float16 f16;
typedef __fp16   fp16x2 __attribute__((ext_vector_type(2)));
typedef _Float16 f16x2t __attribute__((ext_vector_type(2)));
typedef _Float16 f16x8 __attribute__((ext_vector_type(8)));
typedef float    f32x4 __attribute__((ext_vector_type(4)));

__device__ __forceinline__ unsigned pk2r(float a, float b, float& ra, float& rb) {
  fp16x2 h = __builtin_amdgcn_cvt_pkrtz(a, b);   // RTZ pack
  ra = a - (float)h[0];
  rb = b - (float)h[1];
  return __builtin_bit_cast(unsigned, h);
}
__device__ __forceinline__ unsigned pk2(float a, float b) {
  fp16x2 h = __builtin_amdgcn_cvt_pkrtz(a, b);
  return __builtin_bit_cast(unsigned, h);
}
__device__ __forceinline__ unsigned packh(float a, float b) {  // RTN pack
  f16x2t v = {(f16)a, (f16)b};
  return __builtin_bit_cast(unsigned, v);
}
__device__ __forceinline__ float unpk_lo(unsigned u) {
  return (float)__builtin_bit_cast(f16, (unsigned short)(u & 0xffffu));
}
__device__ __forceinline__ float unpk_hi(unsigned u) {
  return (float)__builtin_bit_cast(f16, (unsigned short)(u >> 16));
}

// ---------------- k_xsplit: x -> fragment-order f16 (RTN) -------------------
__global__ __launch_bounds__(256) void k_xsplit(const float* __restrict__ x,
                                                f16* __restrict__ xf) {
  const int idx = blockIdx.x * 256 + threadIdx.x;  // 32768
  const int b  = idx >> 7;
  const int k8 = idx & 127;
  const int kt = k8 >> 2, qh = k8 & 3;
  const int bblk = b >> 4, lm = b & 15;
  float4 a0 = *(const float4*)&x[(size_t)b * 1024 + k8 * 8];
  float4 a1 = *(const float4*)&x[(size_t)b * 1024 + k8 * 8 + 4];
  uint4 H;
  H.x = packh(a0.x, a0.y);
  H.y = packh(a0.z, a0.w);
  H.z = packh(a1.x, a1.y);
  H.w = packh(a1.z, a1.w);
  f16* dst = &xf[(((size_t)(kt * 16 + bblk) * 4 + qh) * 16 + lm) * 8];
  *(uint4*)dst = H;
}

// ---------------- k_base: base[j][b] = (x @ W1)[b][j] + b1[j] (fp32) --------
__global__ __launch_bounds__(256) void k_base(const float* __restrict__ x,
                                              const float* __restrict__ W1,
                                              const float* __restrict__ b1,
                                              float* __restrict__ base) {
  constexpr int STR = 72;
  __shared__ float xsm[32 * STR];
  __shared__ float es[32 * STR];
  const int t  = threadIdx.x;
  const int j0 = blockIdx.x * 64;
  const int b0 = blockIdx.y * 32;
  const int tj = t & 15;
  const int tb = t >> 4;
  float acc[4][2] = {};
  for (int k0 = 0; k0 < 1024; k0 += 32) {
    __syncthreads();
    {
      int bb = t >> 3, kq = t & 7;
      float4 v = *(const float4*)&x[(size_t)(b0 + bb) * 1024 + k0 + kq * 4];
      int kb = kq * 4;
      xsm[(kb + 0) * STR + bb] = v.x;
      xsm[(kb + 1) * STR + bb] = v.y;
      xsm[(kb + 2) * STR + bb] = v.z;
      xsm[(kb + 3) * STR + bb] = v.w;
    }
#pragma unroll
    for (int r = 0; r < 2; ++r) {
      int idx = t + r * 256;
      int k = idx >> 4, jq = idx & 15, col = jq * 4;
      float4 v = *(const float4*)&W1[(size_t)(k0 + k) * 2048 + j0 + col];
      *(float4*)&es[k * STR + col + 4 * (col >> 5)] = v;
    }
    __syncthreads();
#pragma unroll 8
    for (int k = 0; k < 32; ++k) {
      const int ce = tj * 4;
      float4 e = *(const float4*)&es[k * STR + ce + 4 * (ce >> 5)];
      float2 a = *(const float2*)&xsm[k * STR + tb * 2];
      acc[0][0] += e.x * a.x; acc[0][1] += e.x * a.y;
      acc[1][0] += e.y * a.x; acc[1][1] += e.y * a.y;
      acc[2][0] += e.z * a.x; acc[2][1] += e.z * a.y;
      acc[3][0] += e.w * a.x; acc[3][1] += e.w * a.y;
    }
  }
#pragma unroll
  for (int jj = 0; jj < 4; ++jj) {
    int j = j0 + tj * 4 + jj;
    float bv = b1[j];
    float2 o = make_float2(acc[jj][0] + bv, acc[jj][1] + bv);
    *(float2*)&base[(size_t)j * 256 + b0 + tb * 2] = o;
  }
}

// ======= k_big32 v5: j32 x b256, wave 32j x 64b, all-wave staging ===========
// grid (64 jt, 40 p), 256 threads = 4 waves, VGPR cap 128. eA [32 j][64 f16]
// x 2 buffers (4 KB each). ALL threads stage 4 E-dwords/step (sq = t>>5,
// uint2 hi/lo swizzled writes). DEPTH-4 E prefetch (veA..veD[4]). RAW barrier
// per step, vmcnt never drained in-loop. NF-OUTER streaming epilogue.
__global__ __launch_bounds__(256, 2) void k_big32(const f16* __restrict__ xf,
                                                  const float* __restrict__ noise,
                                                  const float* __restrict__ W2,
                                                  const float* __restrict__ base,
                                                  unsigned* __restrict__ ppu) {
  __shared__ __align__(16) char smem[8192];   // eA[0] | eA[1] (4 KB each)
  float* w2l = (float*)smem;       // epilogue overlay (2.7 KB)
  float* e2l = w2l + 320;
  float* e1l = e2l + 320;

  const int t    = threadIdx.x;
  const int jt   = blockIdx.x, p = blockIdx.y;
  const int j0   = jt * 32;
  const int wave = t >> 6, lane = t & 63;
  const int lm   = lane & 15, qh = lane >> 4;
  const int g4   = qh * 4;
  const int bw   = wave * 64;
  const size_t pN = (size_t)p * NPLL;
  const int srow = t & 31, sq = t >> 5;        // staging j-row / k-quad (0..7)
  const int sr7 = srow & 7, cq = sq >> 1, hh = (sq & 1) * 4;
  const int hiOff = ((cq ^ sr7) << 3) + hh;         // f16 units
  const int loOff = (((cq + 4) ^ sr7) << 3) + hh;
  const int aswz = (lm & 7) << 3;

  f16* eA0 = (f16*)smem;
  f16* eA1 = (f16*)(smem + 4096);

  float veA[4], veB[4], veC[4], veD[4];
  f16x8 Ba[4], Bb[4];
  f32x4 acc[2][4];
#pragma unroll
  for (int a = 0; a < 2; ++a)
#pragma unroll
    for (int b = 0; b < 4; ++b) acc[a][b] = (f32x4){0.f, 0.f, 0.f, 0.f};

  const float* Ebase = noise + pN + (size_t)(sq * 4) * 2048 + j0 + srow;
  const int boff = (wave * 4) * 512 + qh * 128 + lm * 8;

  // prologue: E(0..3) into veA..veD; B(0)/B(1) into Ba/Bb
#pragma unroll
  for (int d = 0; d < 4; ++d) veA[d] = Ebase[(size_t)d * 2048];
#pragma unroll
  for (int d = 0; d < 4; ++d) veB[d] = Ebase[65536 + (size_t)d * 2048];
#pragma unroll
  for (int d = 0; d < 4; ++d) veC[d] = Ebase[131072 + (size_t)d * 2048];
#pragma unroll
  for (int d = 0; d < 4; ++d) veD[d] = Ebase[196608 + (size_t)d * 2048];
#pragma unroll
  for (int nf = 0; nf < 4; ++nf)
    Ba[nf] = *(const f16x8*)&xf[boff + nf * 512];
#pragma unroll
  for (int nf = 0; nf < 4; ++nf)
    Bb[nf] = *(const f16x8*)&xf[8192 + boff + nf * 512];

#define KSTEP32(EAC, VE, BF, KS)                                               \
  do {                                                                         \
    { /* cvt VE=E(KS) -> EAC: 4 hi f16 + 4 lo f16, uint2 swizzled writes */    \
      float r0, r1, r2, r3;                                                    \
      uint2 H, L;                                                              \
      H.x = pk2r(VE[0], VE[1], r0, r1);                                        \
      H.y = pk2r(VE[2], VE[3], r2, r3);                                        \
      *(uint2*)&EAC[srow * 64 + hiOff] = H;                                    \
      L.x = pk2(r0, r1); L.y = pk2(r2, r3);                                    \
      *(uint2*)&EAC[srow * 64 + loOff] = L;                                    \
    }                                                                          \
    if ((KS) + 4 < 32) { /* issue E(KS+4): 4 steps in flight */                \
      const float* En = Ebase + (size_t)((KS) + 4) * 65536;                    \
      _Pragma("unroll") for (int d = 0; d < 4; ++d)                            \
        VE[d] = En[(size_t)d * 2048];                                          \
    }                                                                          \
    asm volatile("s_waitcnt lgkmcnt(0)" ::: "memory");  /* ds_writes done */   \
    __builtin_amdgcn_s_barrier();                       /* raw: no vm drain */ \
    asm volatile("" ::: "memory");                                             \
    _Pragma("unroll") for (int mf = 0; mf < 2; ++mf) {                         \
      const int ra = mf * 16 + lm;                                             \
      f16x8 Ah = *(const f16x8*)&EAC[ra * 64 + ((qh * 8) ^ aswz)];             \
      f16x8 Al = *(const f16x8*)&EAC[ra * 64 + (((qh + 4) * 8) ^ aswz)];       \
      _Pragma("unroll") for (int nf = 0; nf < 4; ++nf) {                       \
        acc[mf][nf] = __builtin_amdgcn_mfma_f32_16x16x32_f16(Ah, BF[nf], acc[mf][nf], 0, 0, 0); \
        acc[mf][nf] = __builtin_amdgcn_mfma_f32_16x16x32_f16(Al, BF[nf], acc[mf][nf], 0, 0, 0); \
      }                                                                        \
    }                                                                          \
    if ((KS) + 2 < 32) { /* issue B(KS+2) into BF (WAR after last MFMA) */     \
      const f16* xn = xf + (size_t)((KS) + 2) * 8192;                          \
      _Pragma("unroll") for (int nf = 0; nf < 4; ++nf)                         \
        BF[nf] = *(const f16x8*)&xn[boff + nf * 512];                          \
    }                                                                          \
  } while (0)

  for (int ks = 0; ks < 32; ks += 4) {
    KSTEP32(eA0, veA, Ba, ks);
    KSTEP32(eA1, veB, Bb, ks + 1);
    KSTEP32(eA0, veC, Ba, ks + 2);
    KSTEP32(eA1, veD, Bb, ks + 3);
  }
#undef KSTEP32

  // ---- epilogue: tables overlay dead eA; NF-OUTER streaming (low live) ----
  __syncthreads();
  for (int i = t; i < 320; i += 256) {
    w2l[i] = W2[j0 * 10 + i];
    e2l[i] = noise[pN + S2_ + (size_t)j0 * 10 + i];
  }
  if (t < 32) e1l[t] = noise[pN + S1_ + j0 + t];
  __syncthreads();

#pragma unroll 1
  for (int s = 0; s < 2; ++s) {
    const float sf = s ? -0.1f : 0.1f;
#pragma unroll 1
    for (int nf = 0; nf < 4; ++nf) {
      const int bl = bw + nf * 16 + lm;
      float ppv[10];
#pragma unroll
      for (int o = 0; o < 10; ++o) ppv[o] = 0.f;
#pragma unroll
      for (int mf = 0; mf < 2; ++mf)
#pragma unroll
        for (int r = 0; r < 4; ++r) {
          const int jl = mf * 16 + g4 + r;     // D row = (lane>>4)*4 + reg
          const float bs = base[(size_t)(j0 + jl) * 256 + bl];
          const float h =
              fmaxf(fmaf(sf, acc[mf][nf][r] + e1l[jl], bs), 0.f);
#pragma unroll
          for (int o = 0; o < 10; ++o)
            ppv[o] = fmaf(h, fmaf(sf, e2l[jl * 10 + o], w2l[jl * 10 + o]),
                          ppv[o]);
        }
      // sum the 4 qh row-groups (lane bits 4,5); wave covers all 32 j
#pragma unroll
      for (int o = 0; o < 10; ++o) {
        float v = ppv[o];
        v += __shfl_xor(v, 16, 64);
        v += __shfl_xor(v, 32, 64);
        ppv[o] = v;
      }
      if (lane < 16) {
        const size_t u0 = ((((size_t)p * 2 + s) * 64 + jt) * 256 + bl) * 5;
        ppu[u0 + 0] = packh(ppv[0], ppv[1]);
        ppu[u0 + 1] = packh(ppv[2], ppv[3]);
        ppu[u0 + 2] = packh(ppv[4], ppv[5]);
        ppu[u0 + 3] = packh(ppv[6], ppv[7]);
        ppu[u0 + 4] = packh(ppv[8], ppv[9]);
      }
    }
  }
}

// ======= k_big64: R12's verified kernel (fallback when ws is small) =========
__global__ __launch_bounds__(256) void k_big64(const f16* __restrict__ xf,
                                               const float* __restrict__ noise,
                                               const float* __restrict__ W2,
                                               const float* __restrict__ base,
                                               unsigned* __restrict__ ppu) {
  __shared__ __align__(16) char smem[16384];
  float* w2l = (float*)smem;
  float* e2l = w2l + 640;
  float* e1l = e2l + 640;

  const int t    = threadIdx.x;
  const int jt   = blockIdx.x, p = blockIdx.y;
  const int j0   = jt * 64;
  const int wave = t >> 6, lane = t & 63;
  const int lm   = lane & 15, qh = lane >> 4;
  const int g4   = qh * 4;
  const int bw   = wave * 64;
  const size_t pN = (size_t)p * NPLL;
  const int srow = t & 63, sq = t >> 6;
  const int sswz = (srow & 7) << 3;
  const int aswz = (lm & 7) << 3;

  f16* eA0 = (f16*)smem;
  f16* eA1 = (f16*)(smem + 8192);

  float veA[8], veB[8];
  f16x8 Ba[4], Bb[4];
  f32x4 acc[4][4];
#pragma unroll
  for (int a = 0; a < 4; ++a)
#pragma unroll
    for (int b = 0; b < 4; ++b) acc[a][b] = (f32x4){0.f, 0.f, 0.f, 0.f};

  const float* Ebase = noise + pN + (size_t)(sq * 8) * 2048 + j0 + srow;
  const int boff = (wave * 4) * 512 + qh * 128 + lm * 8;

#pragma unroll
  for (int d = 0; d < 8; ++d) veA[d] = Ebase[(size_t)d * 2048];
#pragma unroll
  for (int nf = 0; nf < 4; ++nf)
    Ba[nf] = *(const f16x8*)&xf[boff + nf * 512];
#pragma unroll
  for (int d = 0; d < 8; ++d) veB[d] = Ebase[65536 + (size_t)d * 2048];
#pragma unroll
  for (int nf = 0; nf < 4; ++nf)
    Bb[nf] = *(const f16x8*)&xf[8192 + boff + nf * 512];

#define KSTEP64(EAC, VE, BF, KS)                                               \
  do {                                                                         \
    {                                                                          \
      float r0, r1, r2, r3, r4, r5, r6, r7;                                    \
      uint4 H, L;                                                              \
      H.x = pk2r(VE[0], VE[1], r0, r1);                                        \
      H.y = pk2r(VE[2], VE[3], r2, r3);                                        \
      H.z = pk2r(VE[4], VE[5], r4, r5);                                        \
      H.w = pk2r(VE[6], VE[7], r6, r7);                                        \
      *(uint4*)&EAC[srow * 64 + ((sq * 8) ^ sswz)] = H;                        \
      L.x = pk2(r0, r1); L.y = pk2(r2, r3);                                    \
      L.z = pk2(r4, r5); L.w = pk2(r6, r7);                                    \
      *(uint4*)&EAC[srow * 64 + (((sq + 4) * 8) ^ sswz)] = L;                  \
    }                                                                          \
    if ((KS) + 2 < 32) {                                                       \
      const float* En = Ebase + (size_t)((KS) + 2) * 65536;                    \
      _Pragma("unroll") for (int d = 0; d < 8; ++d)                            \
        VE[d] = En[(size_t)d * 2048];                                          \
    }                                                                          \
    asm volatile("s_waitcnt lgkmcnt(0)" ::: "memory");                         \
    __builtin_amdgcn_s_barrier();                                              \
    asm volatile("" ::: "memory");                                             \
    _Pragma("unroll") for (int mf = 0; mf < 4; ++mf) {                         \
      const int ra = mf * 16 + lm;                                             \
      f16x8 Ah = *(const f16x8*)&EAC[ra * 64 + ((qh * 8) ^ aswz)];             \
      f16x8 Al = *(const f16x8*)&EAC[ra * 64 + (((qh + 4) * 8) ^ aswz)];       \
      _Pragma("unroll") for (int nf = 0; nf < 4; ++nf) {                       \
        acc[mf][nf] = __builtin_amdgcn_mfma_f32_16x16x32_f16(Ah, BF[nf], acc[mf][nf], 0, 0, 0); \
        acc[mf][nf] = __builtin_amdgcn_mfma_f32_16x16x32_f16(Al, BF[nf], acc[mf][nf], 0, 0, 0); \
      }                                                                        \
    }                                                                          \
    if ((KS) + 2 < 32) {                                                       \
      const f16* xn = xf + (size_t)((KS) + 2) * 8192;                          \
      _Pragma("unroll") for (int nf = 0; nf < 4; ++nf)                         \
        BF[nf] = *(const f16x8*)&xn[boff + nf * 512];                          \
    }                                                                          \
  } while (0)

  for (int ks = 0; ks < 32; ks += 2) {
    KSTEP64(eA0, veA, Ba, ks);
    KSTEP64(eA1, veB, Bb, ks + 1);
  }
#undef KSTEP64

  __syncthreads();
  for (int i = t; i < 640; i += 256) {
    w2l[i] = W2[j0 * 10 + i];
    e2l[i] = noise[pN + S2_ + (size_t)j0 * 10 + i];
  }
  if (t < 64) e1l[t] = noise[pN + S1_ + j0 + t];
  __syncthreads();

#pragma unroll 1
  for (int s = 0; s < 2; ++s) {
    const float sf = s ? -0.1f : 0.1f;
    float ppv[4][10];
#pragma unroll
    for (int nf = 0; nf < 4; ++nf)
#pragma unroll
      for (int o = 0; o < 10; ++o) ppv[nf][o] = 0.f;
#pragma unroll
    for (int mf = 0; mf < 4; ++mf)
#pragma unroll
      for (int r = 0; r < 4; ++r) {
        const int jl = mf * 16 + g4 + r;
        const float e1v = e1l[jl];
        float w2s[10];
#pragma unroll
        for (int o = 0; o < 10; ++o)
          w2s[o] = fmaf(sf, e2l[jl * 10 + o], w2l[jl * 10 + o]);
#pragma unroll
        for (int nf = 0; nf < 4; ++nf) {
          const float bs = base[(size_t)(j0 + jl) * 256 + bw + nf * 16 + lm];
          const float h = fmaxf(fmaf(sf, acc[mf][nf][r] + e1v, bs), 0.f);
#pragma unroll
          for (int o = 0; o < 10; ++o) ppv[nf][o] = fmaf(h, w2s[o], ppv[nf][o]);
        }
      }
#pragma unroll
    for (int nf = 0; nf < 4; ++nf)
#pragma unroll
      for (int o = 0; o < 10; ++o) {
        float v = ppv[nf][o];
        v += __shfl_xor(v, 16, 64);
        v += __shfl_xor(v, 32, 64);
        ppv[nf][o] = v;
      }
    if (lane < 16) {
#pragma unroll
      for (int nf = 0; nf < 4; ++nf) {
        const int bl = bw + nf * 16 + lm;
        const size_t u0 = ((((size_t)p * 2 + s) * 32 + jt) * 256 + bl) * 5;
        ppu[u0 + 0] = packh(ppv[nf][0], ppv[nf][1]);
        ppu[u0 + 1] = packh(ppv[nf][2], ppv[nf][3]);
        ppu[u0 + 2] = packh(ppv[nf][4], ppv[nf][5]);
        ppu[u0 + 3] = packh(ppv[nf][6], ppv[nf][7]);
        ppu[u0 + 4] = packh(ppv[nf][8], ppv[nf][9]);
      }
    }
  }
}

// ---------------- k_loss: 80 losses (JT-parameterized) ----------------------
__global__ __launch_bounds__(256) void k_loss(const unsigned* __restrict__ ppu,
                                              const float* __restrict__ y,
                                              const float* __restrict__ b2,
                                              const float* __restrict__ noise,
                                              float* __restrict__ loss,
                                              int JT) {
  const int b = threadIdx.x;
  const int p = blockIdx.x >> 1, s = blockIdx.x & 1;
  const float sf = s ? -0.1f : 0.1f;
  const size_t pN = (size_t)p * NPLL;
  float pred[10];
#pragma unroll
  for (int o = 0; o < 10; ++o) pred[o] = b2[o] + sf * noise[pN + S3_ + o];
  for (int jt = 0; jt < JT; ++jt) {
    const size_t u0 = ((((size_t)p * 2 + s) * JT + jt) * 256 + b) * 5;
#pragma unroll
    for (int q = 0; q < 5; ++q) {
      unsigned u = ppu[u0 + q];
      pred[2 * q]     += unpk_lo(u);
      pred[2 * q + 1] += unpk_hi(u);
    }
  }
  float e = 0.f;
#pragma unroll
  for (int o = 0; o < 10; ++o) {
    float d = pred[o] - y[b * 10 + o];
    e += d * d;
  }
  __shared__ float red[256];
  red[b] = e;
  __syncthreads();
  for (int st = 128; st > 0; st >>= 1) {
    if (b < st) red[b] += red[b + st];
    __syncthreads();
  }
  if (b == 0) loss[blockIdx.x] = red[0] * (1.0f / 2560.0f);
}

// ---------------- k_rank: stable centered ranks -> pair coefficients --------
__global__ void k_rank(const float* __restrict__ loss, float* __restrict__ g) {
  __shared__ float ls[80];
  __shared__ float rk[80];
  const int t = threadIdx.x;
  if (t < 80) ls[t] = loss[t];
  __syncthreads();
  if (t < 80) {
    float li = ls[t];
    int r = 0;
    for (int j = 0; j < 80; ++j) {
      float lj = ls[j];
      r += (lj < li) || (lj == li && j < t);
    }
    rk[t] = (float)r;
  }
  __syncthreads();
  if (t < 40) g[t] = (rk[2 * t] - rk[2 * t + 1]) * (1.0f / (79.0f * 40.0f));
}

// ---------------- k_grad: out[k] = sum_p noise[p][k] * g[p] -----------------
__global__ __launch_bounds__(256) void k_grad(const float* __restrict__ noise,
                                              const float* __restrict__ g,
                                              float* __restrict__ out) {
  __shared__ float gg[40];
  const int t = threadIdx.x;
  if (t < 40) gg[t] = g[t];
  __syncthreads();
  const long long NH = NPLL / 2;
  long long idx = (long long)blockIdx.x * 256 + t;
  if (idx >= NH) return;
  float2 a = make_float2(0.f, 0.f);
#pragma unroll 8
  for (int p = 0; p < 40; ++p) {
    float2 v = *(const float2*)&noise[(size_t)p * NPLL + idx * 2];
    a.x += v.x * gg[p];
    a.y += v.y * gg[p];
  }
  *(float2*)&out[idx * 2] = a;
}

extern "C" void kernel_launch(void* const* d_in, const int* in_sizes, int n_in,
                              void* d_out, int out_size, void* d_ws, size_t ws_size,
                              hipStream_t stream) {
  const float* x     = (const float*)d_in[0];
  const float* y     = (const float*)d_in[1];
  const float* W1    = (const float*)d_in[2];
  const float* b1    = (const float*)d_in[3];
  const float* W2    = (const float*)d_in[4];
  const float* b2    = (const float*)d_in[5];
  const float* noise = (const float*)d_in[6];
  float* out  = (float*)d_out;
  float* ws   = (float*)d_ws;
  float* base = ws;

  const bool wide = (ws_size >= WW_NEED_BYTES);
  unsigned* ppu = (unsigned*)(ws + (wide ? WW_PP : WS_PP));
  float* loss = ws + (wide ? WW_LOSS : WS_LOSS);
  float* g    = ws + (wide ? WW_G : WS_G);
  f16* xf     = (f16*)(ws + (wide ? WW_XF : WS_XF));

  k_xsplit<<<128, 256, 0, stream>>>(x, xf);
  k_base<<<dim3(32, 8), 256, 0, stream>>>(x, W1, b1, base);
  if (wide)
    k_big32<<<dim3(64, 40), 256, 0, stream>>>(xf, noise, W2, base, ppu);
  else
    k_big64<<<dim3(32, 40), 256, 0, stream>>>(xf, noise, W2, base, ppu);
  k_loss<<<80, 256, 0, stream>>>(ppu, y, b2, noise, loss, wide ? 64 : 32);
  k_rank<<<1, 128, 0, stream>>>(loss, g);
  k_grad<<<4141, 256, 0, stream>>>(noise, g, out);
}

// Round 23
// 330.733 us; speedup vs baseline: 1.0326x; 1.0162x over previous
//
#include <hip/hip_runtime.h>

// ES gradient for 2-layer MLP (D_IN=1024, HID=2048, D_OUT=10, POP=40, STD=0.1).
// Pipeline: k_xsplit -> k_base -> k_big32 (or k_big64 fallback) -> k_loss ->
// k_rank -> k_grad.
// k_big32 v6 = R22 structure with 1-PRODUCT math: E converted RTN f16 (no lo
// residual product; x already f16). Rank margin: R10 measured dropping x-lo
// leaves absmax exactly 2.441e-4; dropping E-lo adds ~1.4x error in quadrature.
// Tripwire: absmax must remain exactly 2.441e-4 (any rank flip -> hard fail ->
// revert to the 2-product R22 kernel).
// LDS: padded rows (40 f16 = 80B stride) -> conflict-free reads, no XOR.
// Laws measured: VGPR cap 128 via (256,2); demand>cap -> deterministic spill
// (WRITE tripwire). Raw s_barrier + lgkmcnt(0) keeps loads in flight. E-BW
// wall ~1.7-2 TB/s at this gather pattern (occupancy/depth/issue all tested).

#define NPLL 2119690LL          // N_PARAMS
#define S1_  2097152            // W1 end
#define S2_  2099200            // b1 end
#define S3_  2119680            // W2 end

// narrow ws layout (f32 units), jt32 fallback:
#define WS_PP   524288
#define WS_LOSS 3801088
#define WS_G    3801168
#define WS_XF   3801216
// wide ws layout (f32 units), jt64: base | ppu 6553600 dw | loss | g | xf
#define WW_PP   524288
#define WW_LOSS 7077888
#define WW_G    7077968
#define WW_XF   7078016
#define WW_NEED_BYTES 28836352ull   // (WW_XF + 131072) * 4

typedef _Float16 f16;
typedef __fp16   fp16x2 __attribute__((ext_vector_type(2)));
typedef _Float16 f16x2t __attribute__((ext_vector_type(2)));
typedef _Float16 f16x8 __attribute__((ext_vector_type(8)));
typedef float    f32x4 __attribute__((ext_vector_type(4)));

__device__ __forceinline__ unsigned pk2r(float a, float b, float& ra, float& rb) {
  fp16x2 h = __builtin_amdgcn_cvt_pkrtz(a, b);   // RTZ pack
  ra = a - (float)h[0];
  rb = b - (float)h[1];
  return __builtin_bit_cast(unsigned, h);
}
__device__ __forceinline__ unsigned pk2(float a, float b) {
  fp16x2 h = __builtin_amdgcn_cvt_pkrtz(a, b);
  return __builtin_bit_cast(unsigned, h);
}
__device__ __forceinline__ unsigned packh(float a, float b) {  // RTN pack
  f16x2t v = {(f16)a, (f16)b};
  return __builtin_bit_cast(unsigned, v);
}
__device__ __forceinline__ float unpk_lo(unsigned u) {
  return (float)__builtin_bit_cast(f16, (unsigned short)(u & 0xffffu));
}
__device__ __forceinline__ float unpk_hi(unsigned u) {
  return (float)__builtin_bit_cast(f16, (unsigned short)(u >> 16));
}

// ---------------- k_xsplit: x -> fragment-order f16 (RTN) -------------------
__global__ __launch_bounds__(256) void k_xsplit(const float* __restrict__ x,
                                                f16* __restrict__ xf) {
  const int idx = blockIdx.x * 256 + threadIdx.x;  // 32768
  const int b  = idx >> 7;
  const int k8 = idx & 127;
  const int kt = k8 >> 2, qh = k8 & 3;
  const int bblk = b >> 4, lm = b & 15;
  float4 a0 = *(const float4*)&x[(size_t)b * 1024 + k8 * 8];
  float4 a1 = *(const float4*)&x[(size_t)b * 1024 + k8 * 8 + 4];
  uint4 H;
  H.x = packh(a0.x, a0.y);
  H.y = packh(a0.z, a0.w);
  H.z = packh(a1.x, a1.y);
  H.w = packh(a1.z, a1.w);
  f16* dst = &xf[(((size_t)(kt * 16 + bblk) * 4 + qh) * 16 + lm) * 8];
  *(uint4*)dst = H;
}

// ---------------- k_base: base[j][b] = (x @ W1)[b][j] + b1[j] (fp32) --------
__global__ __launch_bounds__(256) void k_base(const float* __restrict__ x,
                                              const float* __restrict__ W1,
                                              const float* __restrict__ b1,
                                              float* __restrict__ base) {
  constexpr int STR = 72;
  __shared__ float xsm[32 * STR];
  __shared__ float es[32 * STR];
  const int t  = threadIdx.x;
  const int j0 = blockIdx.x * 64;
  const int b0 = blockIdx.y * 32;
  const int tj = t & 15;
  const int tb = t >> 4;
  float acc[4][2] = {};
  for (int k0 = 0; k0 < 1024; k0 += 32) {
    __syncthreads();
    {
      int bb = t >> 3, kq = t & 7;
      float4 v = *(const float4*)&x[(size_t)(b0 + bb) * 1024 + k0 + kq * 4];
      int kb = kq * 4;
      xsm[(kb + 0) * STR + bb] = v.x;
      xsm[(kb + 1) * STR + bb] = v.y;
      xsm[(kb + 2) * STR + bb] = v.z;
      xsm[(kb + 3) * STR + bb] = v.w;
    }
#pragma unroll
    for (int r = 0; r < 2; ++r) {
      int idx = t + r * 256;
      int k = idx >> 4, jq = idx & 15, col = jq * 4;
      float4 v = *(const float4*)&W1[(size_t)(k0 + k) * 2048 + j0 + col];
      *(float4*)&es[k * STR + col + 4 * (col >> 5)] = v;
    }
    __syncthreads();
#pragma unroll 8
    for (int k = 0; k < 32; ++k) {
      const int ce = tj * 4;
      float4 e = *(const float4*)&es[k * STR + ce + 4 * (ce >> 5)];
      float2 a = *(const float2*)&xsm[k * STR + tb * 2];
      acc[0][0] += e.x * a.x; acc[0][1] += e.x * a.y;
      acc[1][0] += e.y * a.x; acc[1][1] += e.y * a.y;
      acc[2][0] += e.z * a.x; acc[2][1] += e.z * a.y;
      acc[3][0] += e.w * a.x; acc[3][1] += e.w * a.y;
    }
  }
#pragma unroll
  for (int jj = 0; jj < 4; ++jj) {
    int j = j0 + tj * 4 + jj;
    float bv = b1[j];
    float2 o = make_float2(acc[jj][0] + bv, acc[jj][1] + bv);
    *(float2*)&base[(size_t)j * 256 + b0 + tb * 2] = o;
  }
}

// ======= k_big32 v6: j32 x b256, wave 32j x 64b, 1-product (E f16 RTN) ======
// grid (64 jt, 40 p), 256 threads = 4 waves, VGPR cap 128. eA rows padded to
// 40 f16 (80B) -> conflict-free ds reads without XOR. All threads stage 4
// E-dwords/step (RTN f16, uint2 write). Depth-4 E prefetch. RAW barrier/step,
// vmcnt never drained in-loop. NF-OUTER streaming epilogue.
__global__ __launch_bounds__(256, 2) void k_big32(const f16* __restrict__ xf,
                                                  const float* __restrict__ noise,
                                                  const float* __restrict__ W2,
                                                  const float* __restrict__ base,
                                                  unsigned* __restrict__ ppu) {
  __shared__ __align__(16) char smem[5888];   // eA[0] | eA[1], 2560 B each
  float* w2l = (float*)smem;       // epilogue overlay (2.7 KB <= 5.8 KB)
  float* e2l = w2l + 320;
  float* e1l = e2l + 320;

  const int t    = threadIdx.x;
  const int jt   = blockIdx.x, p = blockIdx.y;
  const int j0   = jt * 32;
  const int wave = t >> 6, lane = t & 63;
  const int lm   = lane & 15, qh = lane >> 4;
  const int g4   = qh * 4;
  const int bw   = wave * 64;
  const size_t pN = (size_t)p * NPLL;
  const int srow = t & 31, sq = t >> 5;        // staging j-row / k-quad (0..7)
  const int wOff = srow * 40 + (sq >> 1) * 8 + (sq & 1) * 4;  // f16 units
  constexpr int STR16 = 40;

  f16* eA0 = (f16*)smem;
  f16* eA1 = (f16*)(smem + 2560);

  float veA[4], veB[4], veC[4], veD[4];
  f16x8 Ba[4], Bb[4];
  f32x4 acc[2][4];
#pragma unroll
  for (int a = 0; a < 2; ++a)
#pragma unroll
    for (int b = 0; b < 4; ++b) acc[a][b] = (f32x4){0.f, 0.f, 0.f, 0.f};

  const float* Ebase = noise + pN + (size_t)(sq * 4) * 2048 + j0 + srow;
  const int boff = (wave * 4) * 512 + qh * 128 + lm * 8;

  // prologue: E(0..3) into veA..veD; B(0)/B(1) into Ba/Bb
#pragma unroll
  for (int d = 0; d < 4; ++d) veA[d] = Ebase[(size_t)d * 2048];
#pragma unroll
  for (int d = 0; d < 4; ++d) veB[d] = Ebase[65536 + (size_t)d * 2048];
#pragma unroll
  for (int d = 0; d < 4; ++d) veC[d] = Ebase[131072 + (size_t)d * 2048];
#pragma unroll
  for (int d = 0; d < 4; ++d) veD[d] = Ebase[196608 + (size_t)d * 2048];
#pragma unroll
  for (int nf = 0; nf < 4; ++nf)
    Ba[nf] = *(const f16x8*)&xf[boff + nf * 512];
#pragma unroll
  for (int nf = 0; nf < 4; ++nf)
    Bb[nf] = *(const f16x8*)&xf[8192 + boff + nf * 512];

#define KSTEP32(EAC, VE, BF, KS)                                               \
  do {                                                                         \
    { /* cvt VE=E(KS) -> EAC: 4 f16 RTN, one uint2 write */                    \
      uint2 H;                                                                 \
      H.x = packh(VE[0], VE[1]);                                               \
      H.y = packh(VE[2], VE[3]);                                               \
      *(uint2*)&EAC[wOff] = H;                                                 \
    }                                                                          \
    if ((KS) + 4 < 32) { /* issue E(KS+4): 4 steps in flight */                \
      const float* En = Ebase + (size_t)((KS) + 4) * 65536;                    \
      _Pragma("unroll") for (int d = 0; d < 4; ++d)                            \
        VE[d] = En[(size_t)d * 2048];                                          \
    }                                                                          \
    asm volatile("s_waitcnt lgkmcnt(0)" ::: "memory");  /* ds_writes done */   \
    __builtin_amdgcn_s_barrier();                       /* raw: no vm drain */ \
    asm volatile("" ::: "memory");                                             \
    _Pragma("unroll") for (int mf = 0; mf < 2; ++mf) {                         \
      const int ra = mf * 16 + lm;                                             \
      f16x8 Ah = *(const f16x8*)&EAC[ra * STR16 + qh * 8];                     \
      _Pragma("unroll") for (int nf = 0; nf < 4; ++nf)                         \
        acc[mf][nf] = __builtin_amdgcn_mfma_f32_16x16x32_f16(Ah, BF[nf], acc[mf][nf], 0, 0, 0); \
    }                                                                          \
    if ((KS) + 2 < 32) { /* issue B(KS+2) into BF (WAR after last MFMA) */     \
      const f16* xn = xf + (size_t)((KS) + 2) * 8192;                          \
      _Pragma("unroll") for (int nf = 0; nf < 4; ++nf)                         \
        BF[nf] = *(const f16x8*)&xn[boff + nf * 512];                          \
    }                                                                          \
  } while (0)

  for (int ks = 0; ks < 32; ks += 4) {
    KSTEP32(eA0, veA, Ba, ks);
    KSTEP32(eA1, veB, Bb, ks + 1);
    KSTEP32(eA0, veC, Ba, ks + 2);
    KSTEP32(eA1, veD, Bb, ks + 3);
  }
#undef KSTEP32

  // ---- epilogue: tables overlay dead eA; NF-OUTER streaming (low live) ----
  __syncthreads();
  for (int i = t; i < 320; i += 256) {
    w2l[i] = W2[j0 * 10 + i];
    e2l[i] = noise[pN + S2_ + (size_t)j0 * 10 + i];
  }
  if (t < 32) e1l[t] = noise[pN + S1_ + j0 + t];
  __syncthreads();

#pragma unroll 1
  for (int s = 0; s < 2; ++s) {
    const float sf = s ? -0.1f : 0.1f;
#pragma unroll 1
    for (int nf = 0; nf < 4; ++nf) {
      const int bl = bw + nf * 16 + lm;
      float ppv[10];
#pragma unroll
      for (int o = 0; o < 10; ++o) ppv[o] = 0.f;
#pragma unroll
      for (int mf = 0; mf < 2; ++mf)
#pragma unroll
        for (int r = 0; r < 4; ++r) {
          const int jl = mf * 16 + g4 + r;     // D row = (lane>>4)*4 + reg
          const float bs = base[(size_t)(j0 + jl) * 256 + bl];
          const float h =
              fmaxf(fmaf(sf, acc[mf][nf][r] + e1l[jl], bs), 0.f);
#pragma unroll
          for (int o = 0; o < 10; ++o)
            ppv[o] = fmaf(h, fmaf(sf, e2l[jl * 10 + o], w2l[jl * 10 + o]),
                          ppv[o]);
        }
      // sum the 4 qh row-groups (lane bits 4,5); wave covers all 32 j
#pragma unroll
      for (int o = 0; o < 10; ++o) {
        float v = ppv[o];
        v += __shfl_xor(v, 16, 64);
        v += __shfl_xor(v, 32, 64);
        ppv[o] = v;
      }
      if (lane < 16) {
        const size_t u0 = ((((size_t)p * 2 + s) * 64 + jt) * 256 + bl) * 5;
        ppu[u0 + 0] = packh(ppv[0], ppv[1]);
        ppu[u0 + 1] = packh(ppv[2], ppv[3]);
        ppu[u0 + 2] = packh(ppv[4], ppv[5]);
        ppu[u0 + 3] = packh(ppv[6], ppv[7]);
        ppu[u0 + 4] = packh(ppv[8], ppv[9]);
      }
    }
  }
}

// ======= k_big64: 2-product fallback (small ws); unchanged from R12 =========
__global__ __launch_bounds__(256) void k_big64(const f16* __restrict__ xf,
                                               const float* __restrict__ noise,
                                               const float* __restrict__ W2,
                                               const float* __restrict__ base,
                                               unsigned* __restrict__ ppu) {
  __shared__ __align__(16) char smem[16384];
  float* w2l = (float*)smem;
  float* e2l = w2l + 640;
  float* e1l = e2l + 640;

  const int t    = threadIdx.x;
  const int jt   = blockIdx.x, p = blockIdx.y;
  const int j0   = jt * 64;
  const int wave = t >> 6, lane = t & 63;
  const int lm   = lane & 15, qh = lane >> 4;
  const int g4   = qh * 4;
  const int bw   = wave * 64;
  const size_t pN = (size_t)p * NPLL;
  const int srow = t & 63, sq = t >> 6;
  const int sswz = (srow & 7) << 3;
  const int aswz = (lm & 7) << 3;

  f16* eA0 = (f16*)smem;
  f16* eA1 = (f16*)(smem + 8192);

  float veA[8], veB[8];
  f16x8 Ba[4], Bb[4];
  f32x4 acc[4][4];
#pragma unroll
  for (int a = 0; a < 4; ++a)
#pragma unroll
    for (int b = 0; b < 4; ++b) acc[a][b] = (f32x4){0.f, 0.f, 0.f, 0.f};

  const float* Ebase = noise + pN + (size_t)(sq * 8) * 2048 + j0 + srow;
  const int boff = (wave * 4) * 512 + qh * 128 + lm * 8;

#pragma unroll
  for (int d = 0; d < 8; ++d) veA[d] = Ebase[(size_t)d * 2048];
#pragma unroll
  for (int nf = 0; nf < 4; ++nf)
    Ba[nf] = *(const f16x8*)&xf[boff + nf * 512];
#pragma unroll
  for (int d = 0; d < 8; ++d) veB[d] = Ebase[65536 + (size_t)d * 2048];
#pragma unroll
  for (int nf = 0; nf < 4; ++nf)
    Bb[nf] = *(const f16x8*)&xf[8192 + boff + nf * 512];

#define KSTEP64(EAC, VE, BF, KS)                                               \
  do {                                                                         \
    {                                                                          \
      float r0, r1, r2, r3, r4, r5, r6, r7;                                    \
      uint4 H, L;                                                              \
      H.x = pk2r(VE[0], VE[1], r0, r1);                                        \
      H.y = pk2r(VE[2], VE[3], r2, r3);                                        \
      H.z = pk2r(VE[4], VE[5], r4, r5);                                        \
      H.w = pk2r(VE[6], VE[7], r6, r7);                                        \
      *(uint4*)&EAC[srow * 64 + ((sq * 8) ^ sswz)] = H;                        \
      L.x = pk2(r0, r1); L.y = pk2(r2, r3);                                    \
      L.z = pk2(r4, r5); L.w = pk2(r6, r7);                                    \
      *(uint4*)&EAC[srow * 64 + (((sq + 4) * 8) ^ sswz)] = L;                  \
    }                                                                          \
    if ((KS) + 2 < 32) {                                                       \
      const float* En = Ebase + (size_t)((KS) + 2) * 65536;                    \
      _Pragma("unroll") for (int d = 0; d < 8; ++d)                            \
        VE[d] = En[(size_t)d * 2048];                                          \
    }                                                                          \
    asm volatile("s_waitcnt lgkmcnt(0)" ::: "memory");                         \
    __builtin_amdgcn_s_barrier();                                              \
    asm volatile("" ::: "memory");                                             \
    _Pragma("unroll") for (int mf = 0; mf < 4; ++mf) {                         \
      const int ra = mf * 16 + lm;                                             \
      f16x8 Ah = *(const f16x8*)&EAC[ra * 64 + ((qh * 8) ^ aswz)];             \
      f16x8 Al = *(const f16x8*)&EAC[ra * 64 + (((qh + 4) * 8) ^ aswz)];       \
      _Pragma("unroll") for (int nf = 0; nf < 4; ++nf) {                       \
        acc[mf][nf] = __builtin_amdgcn_mfma_f32_16x16x32_f16(Ah, BF[nf], acc[mf][nf], 0, 0, 0); \
        acc[mf][nf] = __builtin_amdgcn_mfma_f32_16x16x32_f16(Al, BF[nf], acc[mf][nf], 0, 0, 0); \
      }                                                                        \
    }                                                                          \
    if ((KS) + 2 < 32) {                                                       \
      const f16* xn = xf + (size_t)((KS) + 2) * 8192;                          \
      _Pragma("unroll") for (int nf = 0; nf < 4; ++nf)                         \
        BF[nf] = *(const f16x8*)&xn[boff + nf * 512];                          \
    }                                                                          \
  } while (0)

  for (int ks = 0; ks < 32; ks += 2) {
    KSTEP64(eA0, veA, Ba, ks);
    KSTEP64(eA1, veB, Bb, ks + 1);
  }
#undef KSTEP64

  __syncthreads();
  for (int i = t; i < 640; i += 256) {
    w2l[i] = W2[j0 * 10 + i];
    e2l[i] = noise[pN + S2_ + (size_t)j0 * 10 + i];
  }
  if (t < 64) e1l[t] = noise[pN + S1_ + j0 + t];
  __syncthreads();

#pragma unroll 1
  for (int s = 0; s < 2; ++s) {
    const float sf = s ? -0.1f : 0.1f;
    float ppv[4][10];
#pragma unroll
    for (int nf = 0; nf < 4; ++nf)
#pragma unroll
      for (int o = 0; o < 10; ++o) ppv[nf][o] = 0.f;
#pragma unroll
    for (int mf = 0; mf < 4; ++mf)
#pragma unroll
      for (int r = 0; r < 4; ++r) {
        const int jl = mf * 16 + g4 + r;
        const float e1v = e1l[jl];
        float w2s[10];
#pragma unroll
        for (int o = 0; o < 10; ++o)
          w2s[o] = fmaf(sf, e2l[jl * 10 + o], w2l[jl * 10 + o]);
#pragma unroll
        for (int nf = 0; nf < 4; ++nf) {
          const float bs = base[(size_t)(j0 + jl) * 256 + bw + nf * 16 + lm];
          const float h = fmaxf(fmaf(sf, acc[mf][nf][r] + e1v, bs), 0.f);
#pragma unroll
          for (int o = 0; o < 10; ++o) ppv[nf][o] = fmaf(h, w2s[o], ppv[nf][o]);
        }
      }
#pragma unroll
    for (int nf = 0; nf < 4; ++nf)
#pragma unroll
      for (int o = 0; o < 10; ++o) {
        float v = ppv[nf][o];
        v += __shfl_xor(v, 16, 64);
        v += __shfl_xor(v, 32, 64);
        ppv[nf][o] = v;
      }
    if (lane < 16) {
#pragma unroll
      for (int nf = 0; nf < 4; ++nf) {
        const int bl = bw + nf * 16 + lm;
        const size_t u0 = ((((size_t)p * 2 + s) * 32 + jt) * 256 + bl) * 5;
        ppu[u0 + 0] = packh(ppv[nf][0], ppv[nf][1]);
        ppu[u0 + 1] = packh(ppv[nf][2], ppv[nf][3]);
        ppu[u0 + 2] = packh(ppv[nf][4], ppv[nf][5]);
        ppu[u0 + 3] = packh(ppv[nf][6], ppv[nf][7]);
        ppu[u0 + 4] = packh(ppv[nf][8], ppv[nf][9]);
      }
    }
  }
}

// ---------------- k_loss: 80 losses (JT-parameterized) ----------------------
__global__ __launch_bounds__(256) void k_loss(const unsigned* __restrict__ ppu,
                                              const float* __restrict__ y,
                                              const float* __restrict__ b2,
                                              const float* __restrict__ noise,
                                              float* __restrict__ loss,
                                              int JT) {
  const int b = threadIdx.x;
  const int p = blockIdx.x >> 1, s = blockIdx.x & 1;
  const float sf = s ? -0.1f : 0.1f;
  const size_t pN = (size_t)p * NPLL;
  float pred[10];
#pragma unroll
  for (int o = 0; o < 10; ++o) pred[o] = b2[o] + sf * noise[pN + S3_ + o];
  for (int jt = 0; jt < JT; ++jt) {
    const size_t u0 = ((((size_t)p * 2 + s) * JT + jt) * 256 + b) * 5;
#pragma unroll
    for (int q = 0; q < 5; ++q) {
      unsigned u = ppu[u0 + q];
      pred[2 * q]     += unpk_lo(u);
      pred[2 * q + 1] += unpk_hi(u);
    }
  }
  float e = 0.f;
#pragma unroll
  for (int o = 0; o < 10; ++o) {
    float d = pred[o] - y[b * 10 + o];
    e += d * d;
  }
  __shared__ float red[256];
  red[b] = e;
  __syncthreads();
  for (int st = 128; st > 0; st >>= 1) {
    if (b < st) red[b] += red[b + st];
    __syncthreads();
  }
  if (b == 0) loss[blockIdx.x] = red[0] * (1.0f / 2560.0f);
}

// ---------------- k_rank: stable centered ranks -> pair coefficients --------
__global__ void k_rank(const float* __restrict__ loss, float* __restrict__ g) {
  __shared__ float ls[80];
  __shared__ float rk[80];
  const int t = threadIdx.x;
  if (t < 80) ls[t] = loss[t];
  __syncthreads();
  if (t < 80) {
    float li = ls[t];
    int r = 0;
    for (int j = 0; j < 80; ++j) {
      float lj = ls[j];
      r += (lj < li) || (lj == li && j < t);
    }
    rk[t] = (float)r;
  }
  __syncthreads();
  if (t < 40) g[t] = (rk[2 * t] - rk[2 * t + 1]) * (1.0f / (79.0f * 40.0f));
}

// ---------------- k_grad: out[k] = sum_p noise[p][k] * g[p] -----------------
__global__ __launch_bounds__(256) void k_grad(const float* __restrict__ noise,
                                              const float* __restrict__ g,
                                              float* __restrict__ out) {
  __shared__ float gg[40];
  const int t = threadIdx.x;
  if (t < 40) gg[t] = g[t];
  __syncthreads();
  const long long NH = NPLL / 2;
  long long idx = (long long)blockIdx.x * 256 + t;
  if (idx >= NH) return;
  float2 a = make_float2(0.f, 0.f);
#pragma unroll 8
  for (int p = 0; p < 40; ++p) {
    float2 v = *(const float2*)&noise[(size_t)p * NPLL + idx * 2];
    a.x += v.x * gg[p];
    a.y += v.y * gg[p];
  }
  *(float2*)&out[idx * 2] = a;
}

extern "C" void kernel_launch(void* const* d_in, const int* in_sizes, int n_in,
                              void* d_out, int out_size, void* d_ws, size_t ws_size,
                              hipStream_t stream) {
  const float* x     = (const float*)d_in[0];
  const float* y     = (const float*)d_in[1];
  const float* W1    = (const float*)d_in[2];
  const float* b1    = (const float*)d_in[3];
  const float* W2    = (const float*)d_in[4];
  const float* b2    = (const float*)d_in[5];
  const float* noise = (const float*)d_in[6];
  float* out  = (float*)d_out;
  float* ws   = (float*)d_ws;
  float* base = ws;

  const bool wide = (ws_size >= WW_NEED_BYTES);
  unsigned* ppu = (unsigned*)(ws + (wide ? WW_PP : WS_PP));
  float* loss = ws + (wide ? WW_LOSS : WS_LOSS);
  float* g    = ws + (wide ? WW_G : WS_G);
  f16* xf     = (f16*)(ws + (wide ? WW_XF : WS_XF));

  k_xsplit<<<128, 256, 0, stream>>>(x, xf);
  k_base<<<dim3(32, 8), 256, 0, stream>>>(x, W1, b1, base);
  if (wide)
    k_big32<<<dim3(64, 40), 256, 0, stream>>>(xf, noise, W2, base, ppu);
  else
    k_big64<<<dim3(32, 40), 256, 0, stream>>>(xf, noise, W2, base, ppu);
  k_loss<<<80, 256, 0, stream>>>(ppu, y, b2, noise, loss, wide ? 64 : 32);
  k_rank<<<1, 128, 0, stream>>>(loss, g);
  k_grad<<<4141, 256, 0, stream>>>(noise, g, out);
}

// Round 24
// 318.169 us; speedup vs baseline: 1.0733x; 1.0395x over previous
//
#include <hip/hip_runtime.h>

// ES gradient for 2-layer MLP (D_IN=1024, HID=2048, D_OUT=10, POP=40, STD=0.1).
// Pipeline: k_xsplit -> k_base -> k_bigw (or k_big64 fallback) -> k_loss ->
// k_rank -> k_grad.
// k_bigw = 1-product (E f16 RTN x x f16; rank-exact, R23 verified absmax
// 2.441e-4), j64 x b256 block, 512 thr = 8 waves of 32j x 64b. Each wave
// stages one k-quad across 64 j -> E-loads are 256B-contiguous per k-row
// (chunk-size hypothesis: 128B chunks wall at ~1.8-2.0 TB/s, R13 measured
// 2.75 TB/s with 256B chunks). VGPR cap 128 via (512,2); loop live ~95.
// Laws: demand>cap -> deterministic spill (WRITE tripwire). Raw s_barrier +
// lgkmcnt(0) keeps loads in flight. NF-outer epilogue fits the cap (R20).

#define NPLL 2119690LL          // N_PARAMS
#define S1_  2097152            // W1 end
#define S2_  2099200            // b1 end
#define S3_  2119680            // W2 end

// narrow ws layout (f32 units), fallback:
#define WS_PP   524288
#define WS_LOSS 3801088
#define WS_G    3801168
#define WS_XF   3801216
// wide ws layout (f32 units): base | ppu 6553600 dw | loss | g | xf
#define WW_PP   524288
#define WW_LOSS 7077888
#define WW_G    7077968
#define WW_XF   7078016
#define WW_NEED_BYTES 28836352ull   // (WW_XF + 131072) * 4

typedef _Float16 f16;
typedef __fp16   fp16x2 __attribute__((ext_vector_type(2)));
typedef _Float16 f16x2t __attribute__((ext_vector_type(2)));
typedef _Float16 f16x8 __attribute__((ext_vector_type(8)));
typedef float    f32x4 __attribute__((ext_vector_type(4)));

__device__ __forceinline__ unsigned pk2r(float a, float b, float& ra, float& rb) {
  fp16x2 h = __builtin_amdgcn_cvt_pkrtz(a, b);   // RTZ pack
  ra = a - (float)h[0];
  rb = b - (float)h[1];
  return __builtin_bit_cast(unsigned, h);
}
__device__ __forceinline__ unsigned pk2(float a, float b) {
  fp16x2 h = __builtin_amdgcn_cvt_pkrtz(a, b);
  return __builtin_bit_cast(unsigned, h);
}
__device__ __forceinline__ unsigned packh(float a, float b) {  // RTN pack
  f16x2t v = {(f16)a, (f16)b};
  return __builtin_bit_cast(unsigned, v);
}
__device__ __forceinline__ float unpk_lo(unsigned u) {
  return (float)__builtin_bit_cast(f16, (unsigned short)(u & 0xffffu));
}
__device__ __forceinline__ float unpk_hi(unsigned u) {
  return (float)__builtin_bit_cast(f16, (unsigned short)(u >> 16));
}

// ---------------- k_xsplit: x -> fragment-order f16 (RTN) -------------------
__global__ __launch_bounds__(256) void k_xsplit(const float* __restrict__ x,
                                                f16* __restrict__ xf) {
  const int idx = blockIdx.x * 256 + threadIdx.x;  // 32768
  const int b  = idx >> 7;
  const int k8 = idx & 127;
  const int kt = k8 >> 2, qh = k8 & 3;
  const int bblk = b >> 4, lm = b & 15;
  float4 a0 = *(const float4*)&x[(size_t)b * 1024 + k8 * 8];
  float4 a1 = *(const float4*)&x[(size_t)b * 1024 + k8 * 8 + 4];
  uint4 H;
  H.x = packh(a0.x, a0.y);
  H.y = packh(a0.z, a0.w);
  H.z = packh(a1.x, a1.y);
  H.w = packh(a1.z, a1.w);
  f16* dst = &xf[(((size_t)(kt * 16 + bblk) * 4 + qh) * 16 + lm) * 8];
  *(uint4*)dst = H;
}

// ---------------- k_base: base[j][b] = (x @ W1)[b][j] + b1[j] (fp32) --------
__global__ __launch_bounds__(256) void k_base(const float* __restrict__ x,
                                              const float* __restrict__ W1,
                                              const float* __restrict__ b1,
                                              float* __restrict__ base) {
  constexpr int STR = 72;
  __shared__ float xsm[32 * STR];
  __shared__ float es[32 * STR];
  const int t  = threadIdx.x;
  const int j0 = blockIdx.x * 64;
  const int b0 = blockIdx.y * 32;
  const int tj = t & 15;
  const int tb = t >> 4;
  float acc[4][2] = {};
  for (int k0 = 0; k0 < 1024; k0 += 32) {
    __syncthreads();
    {
      int bb = t >> 3, kq = t & 7;
      float4 v = *(const float4*)&x[(size_t)(b0 + bb) * 1024 + k0 + kq * 4];
      int kb = kq * 4;
      xsm[(kb + 0) * STR + bb] = v.x;
      xsm[(kb + 1) * STR + bb] = v.y;
      xsm[(kb + 2) * STR + bb] = v.z;
      xsm[(kb + 3) * STR + bb] = v.w;
    }
#pragma unroll
    for (int r = 0; r < 2; ++r) {
      int idx = t + r * 256;
      int k = idx >> 4, jq = idx & 15, col = jq * 4;
      float4 v = *(const float4*)&W1[(size_t)(k0 + k) * 2048 + j0 + col];
      *(float4*)&es[k * STR + col + 4 * (col >> 5)] = v;
    }
    __syncthreads();
#pragma unroll 8
    for (int k = 0; k < 32; ++k) {
      const int ce = tj * 4;
      float4 e = *(const float4*)&es[k * STR + ce + 4 * (ce >> 5)];
      float2 a = *(const float2*)&xsm[k * STR + tb * 2];
      acc[0][0] += e.x * a.x; acc[0][1] += e.x * a.y;
      acc[1][0] += e.y * a.x; acc[1][1] += e.y * a.y;
      acc[2][0] += e.z * a.x; acc[2][1] += e.z * a.y;
      acc[3][0] += e.w * a.x; acc[3][1] += e.w * a.y;
    }
  }
#pragma unroll
  for (int jj = 0; jj < 4; ++jj) {
    int j = j0 + tj * 4 + jj;
    float bv = b1[j];
    float2 o = make_float2(acc[jj][0] + bv, acc[jj][1] + bv);
    *(float2*)&base[(size_t)j * 256 + b0 + tb * 2] = o;
  }
}

// ======= k_bigw: j64 x b256, 8 waves of 32j x 64b, 1-product ================
// grid (32 jt, 40 p), 512 threads, VGPR cap 128. eA [64 j][40 f16] x 2
// (5120 B each). Wave w stages k-quad w across 64 j (256B/row contiguous).
// Depth-4 E prefetch (4 dwords/thread). RAW barrier/step. NF-outer epilogue.
__global__ __launch_bounds__(512, 2) void k_bigw(const f16* __restrict__ xf,
                                                 const float* __restrict__ noise,
                                                 const float* __restrict__ W2,
                                                 const float* __restrict__ base,
                                                 unsigned* __restrict__ ppu) {
  __shared__ __align__(16) char smem[10240];  // eA[0] | eA[1] (5120 B each)
  float* w2l = (float*)smem;       // epilogue overlay (5.4 KB <= 10 KB)
  float* e2l = w2l + 640;
  float* e1l = e2l + 640;

  const int t    = threadIdx.x;
  const int jt   = blockIdx.x, p = blockIdx.y;
  const int j0   = jt * 64;
  const int wave = t >> 6, lane = t & 63;
  const int lm   = lane & 15, qh = lane >> 4;
  const int g4   = qh * 4;
  const int jw   = (wave & 1) * 32;            // wave's j-half
  const int bq   = wave >> 1, bw = bq * 64;    // wave's b-quarter
  const size_t pN = (size_t)p * NPLL;
  const int srow = lane, sk = wave;            // staging j-row / k-quad (0..7)
  const int wOff = srow * 40 + sk * 4;         // f16 units
  constexpr int STR16 = 40;

  f16* eA0 = (f16*)smem;
  f16* eA1 = (f16*)(smem + 5120);

  float veA[4], veB[4], veC[4], veD[4];
  f16x8 Ba[4], Bb[4];
  f32x4 acc[2][4];
#pragma unroll
  for (int a = 0; a < 2; ++a)
#pragma unroll
    for (int b = 0; b < 4; ++b) acc[a][b] = (f32x4){0.f, 0.f, 0.f, 0.f};

  const float* Ebase = noise + pN + (size_t)(sk * 4) * 2048 + j0 + srow;
  const int boff = (bq * 4) * 512 + qh * 128 + lm * 8;

  // prologue: E(0..3) into veA..veD; B(0)/B(1) into Ba/Bb
#pragma unroll
  for (int d = 0; d < 4; ++d) veA[d] = Ebase[(size_t)d * 2048];
#pragma unroll
  for (int d = 0; d < 4; ++d) veB[d] = Ebase[65536 + (size_t)d * 2048];
#pragma unroll
  for (int d = 0; d < 4; ++d) veC[d] = Ebase[131072 + (size_t)d * 2048];
#pragma unroll
  for (int d = 0; d < 4; ++d) veD[d] = Ebase[196608 + (size_t)d * 2048];
#pragma unroll
  for (int nf = 0; nf < 4; ++nf)
    Ba[nf] = *(const f16x8*)&xf[boff + nf * 512];
#pragma unroll
  for (int nf = 0; nf < 4; ++nf)
    Bb[nf] = *(const f16x8*)&xf[8192 + boff + nf * 512];

#define KSTEP(EAC, VE, BF, KS)                                                 \
  do {                                                                         \
    { /* cvt VE=E(KS) -> EAC: 4 f16 RTN, one uint2 write */                    \
      uint2 H;                                                                 \
      H.x = packh(VE[0], VE[1]);                                               \
      H.y = packh(VE[2], VE[3]);                                               \
      *(uint2*)&EAC[wOff] = H;                                                 \
    }                                                                          \
    if ((KS) + 4 < 32) { /* issue E(KS+4): 4 steps in flight */                \
      const float* En = Ebase + (size_t)((KS) + 4) * 65536;                    \
      _Pragma("unroll") for (int d = 0; d < 4; ++d)                            \
        VE[d] = En[(size_t)d * 2048];                                          \
    }                                                                          \
    asm volatile("s_waitcnt lgkmcnt(0)" ::: "memory");  /* ds_writes done */   \
    __builtin_amdgcn_s_barrier();                       /* raw: no vm drain */ \
    asm volatile("" ::: "memory");                                             \
    _Pragma("unroll") for (int mf = 0; mf < 2; ++mf) {                         \
      const int ra = jw + mf * 16 + lm;                                        \
      f16x8 Ah = *(const f16x8*)&EAC[ra * STR16 + qh * 8];                     \
      _Pragma("unroll") for (int nf = 0; nf < 4; ++nf)                         \
        acc[mf][nf] = __builtin_amdgcn_mfma_f32_16x16x32_f16(Ah, BF[nf], acc[mf][nf], 0, 0, 0); \
    }                                                                          \
    if ((KS) + 2 < 32) { /* issue B(KS+2) into BF (WAR after last MFMA) */     \
      const f16* xn = xf + (size_t)((KS) + 2) * 8192;                          \
      _Pragma("unroll") for (int nf = 0; nf < 4; ++nf)                         \
        BF[nf] = *(const f16x8*)&xn[boff + nf * 512];                          \
    }                                                                          \
  } while (0)

  for (int ks = 0; ks < 32; ks += 4) {
    KSTEP(eA0, veA, Ba, ks);
    KSTEP(eA1, veB, Bb, ks + 1);
    KSTEP(eA0, veC, Ba, ks + 2);
    KSTEP(eA1, veD, Bb, ks + 3);
  }
#undef KSTEP

  // ---- epilogue: tables overlay dead eA; NF-OUTER streaming (low live) ----
  __syncthreads();
  for (int i = t; i < 640; i += 512) {
    w2l[i] = W2[j0 * 10 + i];
    e2l[i] = noise[pN + S2_ + (size_t)j0 * 10 + i];
  }
  if (t < 64) e1l[t] = noise[pN + S1_ + j0 + t];
  __syncthreads();

#pragma unroll 1
  for (int s = 0; s < 2; ++s) {
    const float sf = s ? -0.1f : 0.1f;
#pragma unroll 1
    for (int nf = 0; nf < 4; ++nf) {
      const int bl = bw + nf * 16 + lm;
      float ppv[10];
#pragma unroll
      for (int o = 0; o < 10; ++o) ppv[o] = 0.f;
#pragma unroll
      for (int mf = 0; mf < 2; ++mf)
#pragma unroll
        for (int r = 0; r < 4; ++r) {
          const int jl = jw + mf * 16 + g4 + r;  // D row = (lane>>4)*4 + reg
          const float bs = base[(size_t)(j0 + jl) * 256 + bl];
          const float h =
              fmaxf(fmaf(sf, acc[mf][nf][r] + e1l[jl], bs), 0.f);
#pragma unroll
          for (int o = 0; o < 10; ++o)
            ppv[o] = fmaf(h, fmaf(sf, e2l[jl * 10 + o], w2l[jl * 10 + o]),
                          ppv[o]);
        }
      // sum the 4 qh row-groups (lane bits 4,5); wave covers its 32 j
#pragma unroll
      for (int o = 0; o < 10; ++o) {
        float v = ppv[o];
        v += __shfl_xor(v, 16, 64);
        v += __shfl_xor(v, 32, 64);
        ppv[o] = v;
      }
      if (lane < 16) {
        const size_t u0 =
            ((((size_t)p * 2 + s) * 64 + (jt * 2 + (wave & 1))) * 256 + bl) * 5;
        ppu[u0 + 0] = packh(ppv[0], ppv[1]);
        ppu[u0 + 1] = packh(ppv[2], ppv[3]);
        ppu[u0 + 2] = packh(ppv[4], ppv[5]);
        ppu[u0 + 3] = packh(ppv[6], ppv[7]);
        ppu[u0 + 4] = packh(ppv[8], ppv[9]);
      }
    }
  }
}

// ======= k_big64: 2-product fallback (small ws); unchanged from R12 =========
__global__ __launch_bounds__(256) void k_big64(const f16* __restrict__ xf,
                                               const float* __restrict__ noise,
                                               const float* __restrict__ W2,
                                               const float* __restrict__ base,
                                               unsigned* __restrict__ ppu) {
  __shared__ __align__(16) char smem[16384];
  float* w2l = (float*)smem;
  float* e2l = w2l + 640;
  float* e1l = e2l + 640;

  const int t    = threadIdx.x;
  const int jt   = blockIdx.x, p = blockIdx.y;
  const int j0   = jt * 64;
  const int wave = t >> 6, lane = t & 63;
  const int lm   = lane & 15, qh = lane >> 4;
  const int g4   = qh * 4;
  const int bw   = wave * 64;
  const size_t pN = (size_t)p * NPLL;
  const int srow = t & 63, sq = t >> 6;
  const int sswz = (srow & 7) << 3;
  const int aswz = (lm & 7) << 3;

  f16* eA0 = (f16*)smem;
  f16* eA1 = (f16*)(smem + 8192);

  float veA[8], veB[8];
  f16x8 Ba[4], Bb[4];
  f32x4 acc[4][4];
#pragma unroll
  for (int a = 0; a < 4; ++a)
#pragma unroll
    for (int b = 0; b < 4; ++b) acc[a][b] = (f32x4){0.f, 0.f, 0.f, 0.f};

  const float* Ebase = noise + pN + (size_t)(sq * 8) * 2048 + j0 + srow;
  const int boff = (wave * 4) * 512 + qh * 128 + lm * 8;

#pragma unroll
  for (int d = 0; d < 8; ++d) veA[d] = Ebase[(size_t)d * 2048];
#pragma unroll
  for (int nf = 0; nf < 4; ++nf)
    Ba[nf] = *(const f16x8*)&xf[boff + nf * 512];
#pragma unroll
  for (int d = 0; d < 8; ++d) veB[d] = Ebase[65536 + (size_t)d * 2048];
#pragma unroll
  for (int nf = 0; nf < 4; ++nf)
    Bb[nf] = *(const f16x8*)&xf[8192 + boff + nf * 512];

#define KSTEP64(EAC, VE, BF, KS)                                               \
  do {                                                                         \
    {                                                                          \
      float r0, r1, r2, r3, r4, r5, r6, r7;                                    \
      uint4 H, L;                                                              \
      H.x = pk2r(VE[0], VE[1], r0, r1);                                        \
      H.y = pk2r(VE[2], VE[3], r2, r3);                                        \
      H.z = pk2r(VE[4], VE[5], r4, r5);                                        \
      H.w = pk2r(VE[6], VE[7], r6, r7);                                        \
      *(uint4*)&EAC[srow * 64 + ((sq * 8) ^ sswz)] = H;                        \
      L.x = pk2(r0, r1); L.y = pk2(r2, r3);                                    \
      L.z = pk2(r4, r5); L.w = pk2(r6, r7);                                    \
      *(uint4*)&EAC[srow * 64 + (((sq + 4) * 8) ^ sswz)] = L;                  \
    }                                                                          \
    if ((KS) + 2 < 32) {                                                       \
      const float* En = Ebase + (size_t)((KS) + 2) * 65536;                    \
      _Pragma("unroll") for (int d = 0; d < 8; ++d)                            \
        VE[d] = En[(size_t)d * 2048];                                          \
    }                                                                          \
    asm volatile("s_waitcnt lgkmcnt(0)" ::: "memory");                         \
    __builtin_amdgcn_s_barrier();                                              \
    asm volatile("" ::: "memory");                                             \
    _Pragma("unroll") for (int mf = 0; mf < 4; ++mf) {                         \
      const int ra = mf * 16 + lm;                                             \
      f16x8 Ah = *(const f16x8*)&EAC[ra * 64 + ((qh * 8) ^ aswz)];             \
      f16x8 Al = *(const f16x8*)&EAC[ra * 64 + (((qh + 4) * 8) ^ aswz)];       \
      _Pragma("unroll") for (int nf = 0; nf < 4; ++nf) {                       \
        acc[mf][nf] = __builtin_amdgcn_mfma_f32_16x16x32_f16(Ah, BF[nf], acc[mf][nf], 0, 0, 0); \
        acc[mf][nf] = __builtin_amdgcn_mfma_f32_16x16x32_f16(Al, BF[nf], acc[mf][nf], 0, 0, 0); \
      }                                                                        \
    }                                                                          \
    if ((KS) + 2 < 32) {                                                       \
      const f16* xn = xf + (size_t)((KS) + 2) * 8192;                          \
      _Pragma("unroll") for (int nf = 0; nf < 4; ++nf)                         \
        BF[nf] = *(const f16x8*)&xn[boff + nf * 512];                          \
    }                                                                          \
  } while (0)

  for (int ks = 0; ks < 32; ks += 2) {
    KSTEP64(eA0, veA, Ba, ks);
    KSTEP64(eA1, veB, Bb, ks + 1);
  }
#undef KSTEP64

  __syncthreads();
  for (int i = t; i < 640; i += 256) {
    w2l[i] = W2[j0 * 10 + i];
    e2l[i] = noise[pN + S2_ + (size_t)j0 * 10 + i];
  }
  if (t < 64) e1l[t] = noise[pN + S1_ + j0 + t];
  __syncthreads();

#pragma unroll 1
  for (int s = 0; s < 2; ++s) {
    const float sf = s ? -0.1f : 0.1f;
    float ppv[4][10];
#pragma unroll
    for (int nf = 0; nf < 4; ++nf)
#pragma unroll
      for (int o = 0; o < 10; ++o) ppv[nf][o] = 0.f;
#pragma unroll
    for (int mf = 0; mf < 4; ++mf)
#pragma unroll
      for (int r = 0; r < 4; ++r) {
        const int jl = mf * 16 + g4 + r;
        const float e1v = e1l[jl];
        float w2s[10];
#pragma unroll
        for (int o = 0; o < 10; ++o)
          w2s[o] = fmaf(sf, e2l[jl * 10 + o], w2l[jl * 10 + o]);
#pragma unroll
        for (int nf = 0; nf < 4; ++nf) {
          const float bs = base[(size_t)(j0 + jl) * 256 + bw + nf * 16 + lm];
          const float h = fmaxf(fmaf(sf, acc[mf][nf][r] + e1v, bs), 0.f);
#pragma unroll
          for (int o = 0; o < 10; ++o) ppv[nf][o] = fmaf(h, w2s[o], ppv[nf][o]);
        }
      }
#pragma unroll
    for (int nf = 0; nf < 4; ++nf)
#pragma unroll
      for (int o = 0; o < 10; ++o) {
        float v = ppv[nf][o];
        v += __shfl_xor(v, 16, 64);
        v += __shfl_xor(v, 32, 64);
        ppv[nf][o] = v;
      }
    if (lane < 16) {
#pragma unroll
      for (int nf = 0; nf < 4; ++nf) {
        const int bl = bw + nf * 16 + lm;
        const size_t u0 = ((((size_t)p * 2 + s) * 32 + jt) * 256 + bl) * 5;
        ppu[u0 + 0] = packh(ppv[nf][0], ppv[nf][1]);
        ppu[u0 + 1] = packh(ppv[nf][2], ppv[nf][3]);
        ppu[u0 + 2] = packh(ppv[nf][4], ppv[nf][5]);
        ppu[u0 + 3] = packh(ppv[nf][6], ppv[nf][7]);
        ppu[u0 + 4] = packh(ppv[nf][8], ppv[nf][9]);
      }
    }
  }
}

// ---------------- k_loss: 80 losses (JT-parameterized) ----------------------
__global__ __launch_bounds__(256) void k_loss(const unsigned* __restrict__ ppu,
                                              const float* __restrict__ y,
                                              const float* __restrict__ b2,
                                              const float* __restrict__ noise,
                                              float* __restrict__ loss,
                                              int JT) {
  const int b = threadIdx.x;
  const int p = blockIdx.x >> 1, s = blockIdx.x & 1;
  const float sf = s ? -0.1f : 0.1f;
  const size_t pN = (size_t)p * NPLL;
  float pred[10];
#pragma unroll
  for (int o = 0; o < 10; ++o) pred[o] = b2[o] + sf * noise[pN + S3_ + o];
  for (int jt = 0; jt < JT; ++jt) {
    const size_t u0 = ((((size_t)p * 2 + s) * JT + jt) * 256 + b) * 5;
#pragma unroll
    for (int q = 0; q < 5; ++q) {
      unsigned u = ppu[u0 + q];
      pred[2 * q]     += unpk_lo(u);
      pred[2 * q + 1] += unpk_hi(u);
    }
  }
  float e = 0.f;
#pragma unroll
  for (int o = 0; o < 10; ++o) {
    float d = pred[o] - y[b * 10 + o];
    e += d * d;
  }
  __shared__ float red[256];
  red[b] = e;
  __syncthreads();
  for (int st = 128; st > 0; st >>= 1) {
    if (b < st) red[b] += red[b + st];
    __syncthreads();
  }
  if (b == 0) loss[blockIdx.x] = red[0] * (1.0f / 2560.0f);
}

// ---------------- k_rank: stable centered ranks -> pair coefficients --------
__global__ void k_rank(const float* __restrict__ loss, float* __restrict__ g) {
  __shared__ float ls[80];
  __shared__ float rk[80];
  const int t = threadIdx.x;
  if (t < 80) ls[t] = loss[t];
  __syncthreads();
  if (t < 80) {
    float li = ls[t];
    int r = 0;
    for (int j = 0; j < 80; ++j) {
      float lj = ls[j];
      r += (lj < li) || (lj == li && j < t);
    }
    rk[t] = (float)r;
  }
  __syncthreads();
  if (t < 40) g[t] = (rk[2 * t] - rk[2 * t + 1]) * (1.0f / (79.0f * 40.0f));
}

// ---------------- k_grad: out[k] = sum_p noise[p][k] * g[p] -----------------
__global__ __launch_bounds__(256) void k_grad(const float* __restrict__ noise,
                                              const float* __restrict__ g,
                                              float* __restrict__ out) {
  __shared__ float gg[40];
  const int t = threadIdx.x;
  if (t < 40) gg[t] = g[t];
  __syncthreads();
  const long long NH = NPLL / 2;
  long long idx = (long long)blockIdx.x * 256 + t;
  if (idx >= NH) return;
  float2 a = make_float2(0.f, 0.f);
#pragma unroll 8
  for (int p = 0; p < 40; ++p) {
    float2 v = *(const float2*)&noise[(size_t)p * NPLL + idx * 2];
    a.x += v.x * gg[p];
    a.y += v.y * gg[p];
  }
  *(float2*)&out[idx * 2] = a;
}

extern "C" void kernel_launch(void* const* d_in, const int* in_sizes, int n_in,
                              void* d_out, int out_size, void* d_ws, size_t ws_size,
                              hipStream_t stream) {
  const float* x     = (const float*)d_in[0];
  const float* y     = (const float*)d_in[1];
  const float* W1    = (const float*)d_in[2];
  const float* b1    = (const float*)d_in[3];
  const float* W2    = (const float*)d_in[4];
  const float* b2    = (const float*)d_in[5];
  const float* noise = (const float*)d_in[6];
  float* out  = (float*)d_out;
  float* ws   = (float*)d_ws;
  float* base = ws;

  const bool wide = (ws_size >= WW_NEED_BYTES);
  unsigned* ppu = (unsigned*)(ws + (wide ? WW_PP : WS_PP));
  float* loss = ws + (wide ? WW_LOSS : WS_LOSS);
  float* g    = ws + (wide ? WW_G : WS_G);
  f16* xf     = (f16*)(ws + (wide ? WW_XF : WS_XF));

  k_xsplit<<<128, 256, 0, stream>>>(x, xf);
  k_base<<<dim3(32, 8), 256, 0, stream>>>(x, W1, b1, base);
  if (wide)
    k_bigw<<<dim3(32, 40), 512, 0, stream>>>(xf, noise, W2, base, ppu);
  else
    k_big64<<<dim3(32, 40), 256, 0, stream>>>(xf, noise, W2, base, ppu);
  k_loss<<<80, 256, 0, stream>>>(ppu, y, b2, noise, loss, wide ? 64 : 32);
  k_rank<<<1, 128, 0, stream>>>(loss, g);
  k_grad<<<4141, 256, 0, stream>>>(noise, g, out);
}

// Round 25
// 317.810 us; speedup vs baseline: 1.0746x; 1.0011x over previous
//
#include <hip/hip_runtime.h>

// ES gradient for 2-layer MLP (D_IN=1024, HID=2048, D_OUT=10, POP=40, STD=0.1).
// Pipeline: k_xsplit -> k_base -> k_bigw (or k_big64 fallback) -> k_loss ->
// k_rank -> k_grad.
// k_bigw v2 = R24 (j64 x b256, 8 waves, 1-product E-f16, rank-exact) with
// WIDE E staging: 256 stagers load float2 pairs (8B/lane vs 4B) -> half the
// load instructions at 2x width. Session evidence: all 4B/lane kernels wall
// at 1.5-2.0 TB/s while 16B/lane memset hits 6.8 TB/s on the same chip ->
// per-lane width (L1/TA issue rate) is the wall, not DRAM.
// Laws: VGPR cap = 256/launch_bounds_arg2; demand>cap -> deterministic spill
// (WRITE tripwire). Raw s_barrier + lgkmcnt(0) keeps loads in flight.
// Numerics identical to R24 (same RTN f16 E values) -> absmax must stay
// exactly 2.441406e-4.

#define NPLL 2119690LL          // N_PARAMS
#define S1_  2097152            // W1 end
#define S2_  2099200            // b1 end
#define S3_  2119680            // W2 end

// narrow ws layout (f32 units), fallback:
#define WS_PP   524288
#define WS_LOSS 3801088
#define WS_G    3801168
#define WS_XF   3801216
// wide ws layout (f32 units): base | ppu 6553600 dw | loss | g | xf
#define WW_PP   524288
#define WW_LOSS 7077888
#define WW_G    7077968
#define WW_XF   7078016
#define WW_NEED_BYTES 28836352ull   // (WW_XF + 131072) * 4

typedef _Float16 f16;
typedef __fp16   fp16x2 __attribute__((ext_vector_type(2)));
typedef _Float16 f16x2t __attribute__((ext_vector_type(2)));
typedef _Float16 f16x8 __attribute__((ext_vector_type(8)));
typedef float    f32x4 __attribute__((ext_vector_type(4)));

__device__ __forceinline__ unsigned pk2r(float a, float b, float& ra, float& rb) {
  fp16x2 h = __builtin_amdgcn_cvt_pkrtz(a, b);   // RTZ pack
  ra = a - (float)h[0];
  rb = b - (float)h[1];
  return __builtin_bit_cast(unsigned, h);
}
__device__ __forceinline__ unsigned pk2(float a, float b) {
  fp16x2 h = __builtin_amdgcn_cvt_pkrtz(a, b);
  return __builtin_bit_cast(unsigned, h);
}
__device__ __forceinline__ unsigned packh(float a, float b) {  // RTN pack
  f16x2t v = {(f16)a, (f16)b};
  return __builtin_bit_cast(unsigned, v);
}
__device__ __forceinline__ float unpk_lo(unsigned u) {
  return (float)__builtin_bit_cast(f16, (unsigned short)(u & 0xffffu));
}
__device__ __forceinline__ float unpk_hi(unsigned u) {
  return (float)__builtin_bit_cast(f16, (unsigned short)(u >> 16));
}

// ---------------- k_xsplit: x -> fragment-order f16 (RTN) -------------------
__global__ __launch_bounds__(256) void k_xsplit(const float* __restrict__ x,
                                                f16* __restrict__ xf) {
  const int idx = blockIdx.x * 256 + threadIdx.x;  // 32768
  const int b  = idx >> 7;
  const int k8 = idx & 127;
  const int kt = k8 >> 2, qh = k8 & 3;
  const int bblk = b >> 4, lm = b & 15;
  float4 a0 = *(const float4*)&x[(size_t)b * 1024 + k8 * 8];
  float4 a1 = *(const float4*)&x[(size_t)b * 1024 + k8 * 8 + 4];
  uint4 H;
  H.x = packh(a0.x, a0.y);
  H.y = packh(a0.z, a0.w);
  H.z = packh(a1.x, a1.y);
  H.w = packh(a1.z, a1.w);
  f16* dst = &xf[(((size_t)(kt * 16 + bblk) * 4 + qh) * 16 + lm) * 8];
  *(uint4*)dst = H;
}

// ---------------- k_base: base[j][b] = (x @ W1)[b][j] + b1[j] (fp32) --------
__global__ __launch_bounds__(256) void k_base(const float* __restrict__ x,
                                              const float* __restrict__ W1,
                                              const float* __restrict__ b1,
                                              float* __restrict__ base) {
  constexpr int STR = 72;
  __shared__ float xsm[32 * STR];
  __shared__ float es[32 * STR];
  const int t  = threadIdx.x;
  const int j0 = blockIdx.x * 64;
  const int b0 = blockIdx.y * 32;
  const int tj = t & 15;
  const int tb = t >> 4;
  float acc[4][2] = {};
  for (int k0 = 0; k0 < 1024; k0 += 32) {
    __syncthreads();
    {
      int bb = t >> 3, kq = t & 7;
      float4 v = *(const float4*)&x[(size_t)(b0 + bb) * 1024 + k0 + kq * 4];
      int kb = kq * 4;
      xsm[(kb + 0) * STR + bb] = v.x;
      xsm[(kb + 1) * STR + bb] = v.y;
      xsm[(kb + 2) * STR + bb] = v.z;
      xsm[(kb + 3) * STR + bb] = v.w;
    }
#pragma unroll
    for (int r = 0; r < 2; ++r) {
      int idx = t + r * 256;
      int k = idx >> 4, jq = idx & 15, col = jq * 4;
      float4 v = *(const float4*)&W1[(size_t)(k0 + k) * 2048 + j0 + col];
      *(float4*)&es[k * STR + col + 4 * (col >> 5)] = v;
    }
    __syncthreads();
#pragma unroll 8
    for (int k = 0; k < 32; ++k) {
      const int ce = tj * 4;
      float4 e = *(const float4*)&es[k * STR + ce + 4 * (ce >> 5)];
      float2 a = *(const float2*)&xsm[k * STR + tb * 2];
      acc[0][0] += e.x * a.x; acc[0][1] += e.x * a.y;
      acc[1][0] += e.y * a.x; acc[1][1] += e.y * a.y;
      acc[2][0] += e.z * a.x; acc[2][1] += e.z * a.y;
      acc[3][0] += e.w * a.x; acc[3][1] += e.w * a.y;
    }
  }
#pragma unroll
  for (int jj = 0; jj < 4; ++jj) {
    int j = j0 + tj * 4 + jj;
    float bv = b1[j];
    float2 o = make_float2(acc[jj][0] + bv, acc[jj][1] + bv);
    *(float2*)&base[(size_t)j * 256 + b0 + tb * 2] = o;
  }
}

// ======= k_bigw v2: j64 x b256, 8 waves of 32j x 64b, wide E staging ========
// grid (32 jt, 40 p), 512 threads, VGPR cap 128. eA [64 j][40 f16] x 2
// (5120 B each). Stagers t<256: slot (kp = t>>4, jg = t&15) loads float2
// pairs from rows 2kp,2kp+1 (8B/lane), packs 4 k-pair u32, 4 ds_write_b32.
// Depth-4 E prefetch. RAW barrier/step. NF-outer epilogue (R20 verified).
__global__ __launch_bounds__(512, 2) void k_bigw(const f16* __restrict__ xf,
                                                 const float* __restrict__ noise,
                                                 const float* __restrict__ W2,
                                                 const float* __restrict__ base,
                                                 unsigned* __restrict__ ppu) {
  __shared__ __align__(16) char smem[10240];  // eA[0] | eA[1] (5120 B each)
  float* w2l = (float*)smem;       // epilogue overlay (5.4 KB <= 10 KB)
  float* e2l = w2l + 640;
  float* e1l = e2l + 640;

  const int t    = threadIdx.x;
  const int jt   = blockIdx.x, p = blockIdx.y;
  const int j0   = jt * 64;
  const int wave = t >> 6, lane = t & 63;
  const int lm   = lane & 15, qh = lane >> 4;
  const int g4   = qh * 4;
  const int jw   = (wave & 1) * 32;            // wave's j-half
  const int bq   = wave >> 1, bw = bq * 64;    // wave's b-quarter
  const size_t pN = (size_t)p * NPLL;
  const bool stager = (t < 256);
  const int kp = t >> 4, jg = t & 15;          // k-pair 0..15 / j-quad 0..15
  constexpr int STR16 = 40;

  f16* eA0 = (f16*)smem;
  f16* eA1 = (f16*)(smem + 5120);

  // depth-4 E prefetch state: per slot 4 float2 (rows 2kp,2kp+1; j 0..3)
  float2 pa0, pa1, pb0, pb1;   // slot A
  float2 qa0, qa1, qb0, qb1;   // slot B
  float2 ra0, ra1, rb0, rb1;   // slot C
  float2 sa0, sa1, sb0, sb1;   // slot D
  f16x8 Ba[4], Bb[4];
  f32x4 acc[2][4];
#pragma unroll
  for (int a = 0; a < 2; ++a)
#pragma unroll
    for (int b = 0; b < 4; ++b) acc[a][b] = (f32x4){0.f, 0.f, 0.f, 0.f};

  const float* Eb0 = noise + pN + (size_t)(2 * kp) * 2048 + j0 + jg * 4;
  const int boff = (bq * 4) * 512 + qh * 128 + lm * 8;

#define LOADE(A0, A1, B0, B1, KS)                                              \
  do {                                                                         \
    const float* r_ = Eb0 + (size_t)(KS) * 65536;                              \
    A0 = *(const float2*)r_;                                                   \
    A1 = *(const float2*)(r_ + 2);                                             \
    B0 = *(const float2*)(r_ + 2048);                                          \
    B1 = *(const float2*)(r_ + 2050);                                          \
  } while (0)

  // prologue: E(0..3); B(0)/B(1)
  if (stager) {
    LOADE(pa0, pa1, pb0, pb1, 0);
    LOADE(qa0, qa1, qb0, qb1, 1);
    LOADE(ra0, ra1, rb0, rb1, 2);
    LOADE(sa0, sa1, sb0, sb1, 3);
  }
#pragma unroll
  for (int nf = 0; nf < 4; ++nf)
    Ba[nf] = *(const f16x8*)&xf[boff + nf * 512];
#pragma unroll
  for (int nf = 0; nf < 4; ++nf)
    Bb[nf] = *(const f16x8*)&xf[8192 + boff + nf * 512];

#define KSTEP(EAC, A0, A1, B0, B1, BF, KS)                                     \
  do {                                                                         \
    if (stager) { /* cvt slot -> EAC: 4 k-pair u32 at j stride 40 f16 */       \
      unsigned u0 = packh(A0.x, B0.x);                                         \
      unsigned u1 = packh(A0.y, B0.y);                                         \
      unsigned u2 = packh(A1.x, B1.x);                                         \
      unsigned u3 = packh(A1.y, B1.y);                                         \
      f16* w_ = EAC + jg * 160 + kp * 2;                                       \
      *(unsigned*)(w_) = u0;                                                   \
      *(unsigned*)(w_ + 40) = u1;                                              \
      *(unsigned*)(w_ + 80) = u2;                                              \
      *(unsigned*)(w_ + 120) = u3;                                             \
      if ((KS) + 4 < 32) LOADE(A0, A1, B0, B1, (KS) + 4);                      \
    }                                                                          \
    asm volatile("s_waitcnt lgkmcnt(0)" ::: "memory");  /* ds_writes done */   \
    __builtin_amdgcn_s_barrier();                       /* raw: no vm drain */ \
    asm volatile("" ::: "memory");                                             \
    _Pragma("unroll") for (int mf = 0; mf < 2; ++mf) {                         \
      const int ra_ = jw + mf * 16 + lm;                                       \
      f16x8 Ah = *(const f16x8*)&EAC[ra_ * STR16 + qh * 8];                    \
      _Pragma("unroll") for (int nf = 0; nf < 4; ++nf)                         \
        acc[mf][nf] = __builtin_amdgcn_mfma_f32_16x16x32_f16(Ah, BF[nf], acc[mf][nf], 0, 0, 0); \
    }                                                                          \
    if ((KS) + 2 < 32) { /* issue B(KS+2) into BF (WAR after last MFMA) */     \
      const f16* xn = xf + (size_t)((KS) + 2) * 8192;                          \
      _Pragma("unroll") for (int nf = 0; nf < 4; ++nf)                         \
        BF[nf] = *(const f16x8*)&xn[boff + nf * 512];                          \
    }                                                                          \
  } while (0)

  for (int ks = 0; ks < 32; ks += 4) {
    KSTEP(eA0, pa0, pa1, pb0, pb1, Ba, ks);
    KSTEP(eA1, qa0, qa1, qb0, qb1, Bb, ks + 1);
    KSTEP(eA0, ra0, ra1, rb0, rb1, Ba, ks + 2);
    KSTEP(eA1, sa0, sa1, sb0, sb1, Bb, ks + 3);
  }
#undef KSTEP
#undef LOADE

  // ---- epilogue: tables overlay dead eA; NF-OUTER streaming (low live) ----
  __syncthreads();
  for (int i = t; i < 640; i += 512) {
    w2l[i] = W2[j0 * 10 + i];
    e2l[i] = noise[pN + S2_ + (size_t)j0 * 10 + i];
  }
  if (t < 64) e1l[t] = noise[pN + S1_ + j0 + t];
  __syncthreads();

#pragma unroll 1
  for (int s = 0; s < 2; ++s) {
    const float sf = s ? -0.1f : 0.1f;
#pragma unroll 1
    for (int nf = 0; nf < 4; ++nf) {
      const int bl = bw + nf * 16 + lm;
      float ppv[10];
#pragma unroll
      for (int o = 0; o < 10; ++o) ppv[o] = 0.f;
#pragma unroll
      for (int mf = 0; mf < 2; ++mf)
#pragma unroll
        for (int r = 0; r < 4; ++r) {
          const int jl = jw + mf * 16 + g4 + r;  // D row = (lane>>4)*4 + reg
          const float bs = base[(size_t)(j0 + jl) * 256 + bl];
          const float h =
              fmaxf(fmaf(sf, acc[mf][nf][r] + e1l[jl], bs), 0.f);
#pragma unroll
          for (int o = 0; o < 10; ++o)
            ppv[o] = fmaf(h, fmaf(sf, e2l[jl * 10 + o], w2l[jl * 10 + o]),
                          ppv[o]);
        }
      // sum the 4 qh row-groups (lane bits 4,5); wave covers its 32 j
#pragma unroll
      for (int o = 0; o < 10; ++o) {
        float v = ppv[o];
        v += __shfl_xor(v, 16, 64);
        v += __shfl_xor(v, 32, 64);
        ppv[o] = v;
      }
      if (lane < 16) {
        const size_t u0 =
            ((((size_t)p * 2 + s) * 64 + (jt * 2 + (wave & 1))) * 256 + bl) * 5;
        ppu[u0 + 0] = packh(ppv[0], ppv[1]);
        ppu[u0 + 1] = packh(ppv[2], ppv[3]);
        ppu[u0 + 2] = packh(ppv[4], ppv[5]);
        ppu[u0 + 3] = packh(ppv[6], ppv[7]);
        ppu[u0 + 4] = packh(ppv[8], ppv[9]);
      }
    }
  }
}

// ======= k_big64: 2-product fallback (small ws); unchanged from R12 =========
__global__ __launch_bounds__(256) void k_big64(const f16* __restrict__ xf,
                                               const float* __restrict__ noise,
                                               const float* __restrict__ W2,
                                               const float* __restrict__ base,
                                               unsigned* __restrict__ ppu) {
  __shared__ __align__(16) char smem[16384];
  float* w2l = (float*)smem;
  float* e2l = w2l + 640;
  float* e1l = e2l + 640;

  const int t    = threadIdx.x;
  const int jt   = blockIdx.x, p = blockIdx.y;
  const int j0   = jt * 64;
  const int wave = t >> 6, lane = t & 63;
  const int lm   = lane & 15, qh = lane >> 4;
  const int g4   = qh * 4;
  const int bw   = wave * 64;
  const size_t pN = (size_t)p * NPLL;
  const int srow = t & 63, sq = t >> 6;
  const int sswz = (srow & 7) << 3;
  const int aswz = (lm & 7) << 3;

  f16* eA0 = (f16*)smem;
  f16* eA1 = (f16*)(smem + 8192);

  float veA[8], veB[8];
  f16x8 Ba[4], Bb[4];
  f32x4 acc[4][4];
#pragma unroll
  for (int a = 0; a < 4; ++a)
#pragma unroll
    for (int b = 0; b < 4; ++b) acc[a][b] = (f32x4){0.f, 0.f, 0.f, 0.f};

  const float* Ebase = noise + pN + (size_t)(sq * 8) * 2048 + j0 + srow;
  const int boff = (wave * 4) * 512 + qh * 128 + lm * 8;

#pragma unroll
  for (int d = 0; d < 8; ++d) veA[d] = Ebase[(size_t)d * 2048];
#pragma unroll
  for (int nf = 0; nf < 4; ++nf)
    Ba[nf] = *(const f16x8*)&xf[boff + nf * 512];
#pragma unroll
  for (int d = 0; d < 8; ++d) veB[d] = Ebase[65536 + (size_t)d * 2048];
#pragma unroll
  for (int nf = 0; nf < 4; ++nf)
    Bb[nf] = *(const f16x8*)&xf[8192 + boff + nf * 512];

#define KSTEP64(EAC, VE, BF, KS)                                               \
  do {                                                                         \
    {                                                                          \
      float r0, r1, r2, r3, r4, r5, r6, r7;                                    \
      uint4 H, L;                                                              \
      H.x = pk2r(VE[0], VE[1], r0, r1);                                        \
      H.y = pk2r(VE[2], VE[3], r2, r3);                                        \
      H.z = pk2r(VE[4], VE[5], r4, r5);                                        \
      H.w = pk2r(VE[6], VE[7], r6, r7);                                        \
      *(uint4*)&EAC[srow * 64 + ((sq * 8) ^ sswz)] = H;                        \
      L.x = pk2(r0, r1); L.y = pk2(r2, r3);                                    \
      L.z = pk2(r4, r5); L.w = pk2(r6, r7);                                    \
      *(uint4*)&EAC[srow * 64 + (((sq + 4) * 8) ^ sswz)] = L;                  \
    }                                                                          \
    if ((KS) + 2 < 32) {                                                       \
      const float* En = Ebase + (size_t)((KS) + 2) * 65536;                    \
      _Pragma("unroll") for (int d = 0; d < 8; ++d)                            \
        VE[d] = En[(size_t)d * 2048];                                          \
    }                                                                          \
    asm volatile("s_waitcnt lgkmcnt(0)" ::: "memory");                         \
    __builtin_amdgcn_s_barrier();                                              \
    asm volatile("" ::: "memory");                                             \
    _Pragma("unroll") for (int mf = 0; mf < 4; ++mf) {                         \
      const int ra = mf * 16 + lm;                                             \
      f16x8 Ah = *(const f16x8*)&EAC[ra * 64 + ((qh * 8) ^ aswz)];             \
      f16x8 Al = *(const f16x8*)&EAC[ra * 64 + (((qh + 4) * 8) ^ aswz)];       \
      _Pragma("unroll") for (int nf = 0; nf < 4; ++nf) {                       \
        acc[mf][nf] = __builtin_amdgcn_mfma_f32_16x16x32_f16(Ah, BF[nf], acc[mf][nf], 0, 0, 0); \
        acc[mf][nf] = __builtin_amdgcn_mfma_f32_16x16x32_f16(Al, BF[nf], acc[mf][nf], 0, 0, 0); \
      }                                                                        \
    }                                                                          \
    if ((KS) + 2 < 32) {                                                       \
      const f16* xn = xf + (size_t)((KS) + 2) * 8192;                          \
      _Pragma("unroll") for (int nf = 0; nf < 4; ++nf)                         \
        BF[nf] = *(const f16x8*)&xn[boff + nf * 512];                          \
    }                                                                          \
  } while (0)

  for (int ks = 0; ks < 32; ks += 2) {
    KSTEP64(eA0, veA, Ba, ks);
    KSTEP64(eA1, veB, Bb, ks + 1);
  }
#undef KSTEP64

  __syncthreads();
  for (int i = t; i < 640; i += 256) {
    w2l[i] = W2[j0 * 10 + i];
    e2l[i] = noise[pN + S2_ + (size_t)j0 * 10 + i];
  }
  if (t < 64) e1l[t] = noise[pN + S1_ + j0 + t];
  __syncthreads();

#pragma unroll 1
  for (int s = 0; s < 2; ++s) {
    const float sf = s ? -0.1f : 0.1f;
    float ppv[4][10];
#pragma unroll
    for (int nf = 0; nf < 4; ++nf)
#pragma unroll
      for (int o = 0; o < 10; ++o) ppv[nf][o] = 0.f;
#pragma unroll
    for (int mf = 0; mf < 4; ++mf)
#pragma unroll
      for (int r = 0; r < 4; ++r) {
        const int jl = mf * 16 + g4 + r;
        const float e1v = e1l[jl];
        float w2s[10];
#pragma unroll
        for (int o = 0; o < 10; ++o)
          w2s[o] = fmaf(sf, e2l[jl * 10 + o], w2l[jl * 10 + o]);
#pragma unroll
        for (int nf = 0; nf < 4; ++nf) {
          const float bs = base[(size_t)(j0 + jl) * 256 + bw + nf * 16 + lm];
          const float h = fmaxf(fmaf(sf, acc[mf][nf][r] + e1v, bs), 0.f);
#pragma unroll
          for (int o = 0; o < 10; ++o) ppv[nf][o] = fmaf(h, w2s[o], ppv[nf][o]);
        }
      }
#pragma unroll
    for (int nf = 0; nf < 4; ++nf)
#pragma unroll
      for (int o = 0; o < 10; ++o) {
        float v = ppv[nf][o];
        v += __shfl_xor(v, 16, 64);
        v += __shfl_xor(v, 32, 64);
        ppv[nf][o] = v;
      }
    if (lane < 16) {
#pragma unroll
      for (int nf = 0; nf < 4; ++nf) {
        const int bl = bw + nf * 16 + lm;
        const size_t u0 = ((((size_t)p * 2 + s) * 32 + jt) * 256 + bl) * 5;
        ppu[u0 + 0] = packh(ppv[nf][0], ppv[nf][1]);
        ppu[u0 + 1] = packh(ppv[nf][2], ppv[nf][3]);
        ppu[u0 + 2] = packh(ppv[nf][4], ppv[nf][5]);
        ppu[u0 + 3] = packh(ppv[nf][6], ppv[nf][7]);
        ppu[u0 + 4] = packh(ppv[nf][8], ppv[nf][9]);
      }
    }
  }
}

// ---------------- k_loss: 80 losses (JT-parameterized) ----------------------
__global__ __launch_bounds__(256) void k_loss(const unsigned* __restrict__ ppu,
                                              const float* __restrict__ y,
                                              const float* __restrict__ b2,
                                              const float* __restrict__ noise,
                                              float* __restrict__ loss,
                                              int JT) {
  const int b = threadIdx.x;
  const int p = blockIdx.x >> 1, s = blockIdx.x & 1;
  const float sf = s ? -0.1f : 0.1f;
  const size_t pN = (size_t)p * NPLL;
  float pred[10];
#pragma unroll
  for (int o = 0; o < 10; ++o) pred[o] = b2[o] + sf * noise[pN + S3_ + o];
  for (int jt = 0; jt < JT; ++jt) {
    const size_t u0 = ((((size_t)p * 2 + s) * JT + jt) * 256 + b) * 5;
#pragma unroll
    for (int q = 0; q < 5; ++q) {
      unsigned u = ppu[u0 + q];
      pred[2 * q]     += unpk_lo(u);
      pred[2 * q + 1] += unpk_hi(u);
    }
  }
  float e = 0.f;
#pragma unroll
  for (int o = 0; o < 10; ++o) {
    float d = pred[o] - y[b * 10 + o];
    e += d * d;
  }
  __shared__ float red[256];
  red[b] = e;
  __syncthreads();
  for (int st = 128; st > 0; st >>= 1) {
    if (b < st) red[b] += red[b + st];
    __syncthreads();
  }
  if (b == 0) loss[blockIdx.x] = red[0] * (1.0f / 2560.0f);
}

// ---------------- k_rank: stable centered ranks -> pair coefficients --------
__global__ void k_rank(const float* __restrict__ loss, float* __restrict__ g) {
  __shared__ float ls[80];
  __shared__ float rk[80];
  const int t = threadIdx.x;
  if (t < 80) ls[t] = loss[t];
  __syncthreads();
  if (t < 80) {
    float li = ls[t];
    int r = 0;
    for (int j = 0; j < 80; ++j) {
      float lj = ls[j];
      r += (lj < li) || (lj == li && j < t);
    }
    rk[t] = (float)r;
  }
  __syncthreads();
  if (t < 40) g[t] = (rk[2 * t] - rk[2 * t + 1]) * (1.0f / (79.0f * 40.0f));
}

// ---------------- k_grad: out[k] = sum_p noise[p][k] * g[p] -----------------
__global__ __launch_bounds__(256) void k_grad(const float* __restrict__ noise,
                                              const float* __restrict__ g,
                                              float* __restrict__ out) {
  __shared__ float gg[40];
  const int t = threadIdx.x;
  if (t < 40) gg[t] = g[t];
  __syncthreads();
  const long long NH = NPLL / 2;
  long long idx = (long long)blockIdx.x * 256 + t;
  if (idx >= NH) return;
  float2 a = make_float2(0.f, 0.f);
#pragma unroll 8
  for (int p = 0; p < 40; ++p) {
    float2 v = *(const float2*)&noise[(size_t)p * NPLL + idx * 2];
    a.x += v.x * gg[p];
    a.y += v.y * gg[p];
  }
  *(float2*)&out[idx * 2] = a;
}

extern "C" void kernel_launch(void* const* d_in, const int* in_sizes, int n_in,
                              void* d_out, int out_size, void* d_ws, size_t ws_size,
                              hipStream_t stream) {
  const float* x     = (const float*)d_in[0];
  const float* y     = (const float*)d_in[1];
  const float* W1    = (const float*)d_in[2];
  const float* b1    = (const float*)d_in[3];
  const float* W2    = (const float*)d_in[4];
  const float* b2    = (const float*)d_in[5];
  const float* noise = (const float*)d_in[6];
  float* out  = (float*)d_out;
  float* ws   = (float*)d_ws;
  float* base = ws;

  const bool wide = (ws_size >= WW_NEED_BYTES);
  unsigned* ppu = (unsigned*)(ws + (wide ? WW_PP : WS_PP));
  float* loss = ws + (wide ? WW_LOSS : WS_LOSS);
  float* g    = ws + (wide ? WW_G : WS_G);
  f16* xf     = (f16*)(ws + (wide ? WW_XF : WS_XF));

  k_xsplit<<<128, 256, 0, stream>>>(x, xf);
  k_base<<<dim3(32, 8), 256, 0, stream>>>(x, W1, b1, base);
  if (wide)
    k_bigw<<<dim3(32, 40), 512, 0, stream>>>(xf, noise, W2, base, ppu);
  else
    k_big64<<<dim3(32, 40), 256, 0, stream>>>(xf, noise, W2, base, ppu);
  k_loss<<<80, 256, 0, stream>>>(ppu, y, b2, noise, loss, wide ? 64 : 32);
  k_rank<<<1, 128, 0, stream>>>(loss, g);
  k_grad<<<4141, 256, 0, stream>>>(noise, g, out);
}